// Round 1
// baseline (3191.287 us; speedup 1.0000x reference)
//
#include <hip/hip_runtime.h>
#include <hip/hip_bf16.h>

// GCN autoencoder: h=x@Wc; agg = D^-1/2 (A+I) D^-1/2 h + bc; relu;
// z=h@Wl+bl; d=relu(z@Wd1+bd1); out=d@Wd2+bd2.
// N=100000, E=1600000, D=256, H0=128, H1=64.

#define N_DIM 256
#define H0 128
#define H1 64

// ---------------------------------------------------------------- deg kernels
__global__ __launch_bounds__(256) void fill_deg(float* __restrict__ deg, int n) {
    int i = blockIdx.x * 256 + threadIdx.x;
    if (i < n) deg[i] = 1.0f;  // self-loop contributes 1 to every node
}

__global__ __launch_bounds__(256) void count_deg(const int* __restrict__ dst,
                                                 float* __restrict__ deg, int E) {
    int stride = gridDim.x * 256;
    for (int e = blockIdx.x * 256 + threadIdx.x; e < E; e += stride) {
        unsafeAtomicAdd(&deg[dst[e]], 1.0f);
    }
}

// dis = rsqrt(deg) (deg>=1 always); agg[i][:] = h[i][:]*dis^2 + b_conv  (self-loop + bias)
__global__ __launch_bounds__(256) void finalize_dis_init_agg(
    float* __restrict__ deg, const float* __restrict__ h,
    const float* __restrict__ b_conv, float* __restrict__ agg, int n) {
    int gid  = (blockIdx.x * 256 + threadIdx.x) >> 5;   // 32 lanes per node
    int lane = threadIdx.x & 31;
    if (gid >= n) return;
    float dis = rsqrtf(deg[gid]);       // all lanes read before any store (lockstep)
    if (lane == 0) deg[gid] = dis;      // deg buffer becomes dis buffer
    float s = dis * dis;
    float4 hv = *(const float4*)&h[(size_t)gid * H0 + lane * 4];
    float4 bv = *(const float4*)&b_conv[lane * 4];
    float4 o  = make_float4(fmaf(hv.x, s, bv.x), fmaf(hv.y, s, bv.y),
                            fmaf(hv.z, s, bv.z), fmaf(hv.w, s, bv.w));
    *(float4*)&agg[(size_t)gid * H0 + lane * 4] = o;
}

// ---------------------------------------------------------------- scatter
// agg[c][:] += h[r][:] * dis[r]*dis[c] for each edge (r,c). 32 lanes/edge, float4.
__global__ __launch_bounds__(256) void scatter_edges(
    const int* __restrict__ src, const int* __restrict__ dst,
    const float* __restrict__ dis, const float* __restrict__ h,
    float* __restrict__ agg, int E) {
    int gid  = (blockIdx.x * 256 + threadIdx.x) >> 5;
    int lane = threadIdx.x & 31;
    int ng   = (gridDim.x * 256) >> 5;
    for (int e = gid; e < E; e += ng) {
        int r = src[e], c = dst[e];
        float norm = dis[r] * dis[c];
        float4 v = *(const float4*)&h[(size_t)r * H0 + lane * 4];
        size_t o = (size_t)c * H0 + lane * 4;
        unsafeAtomicAdd(&agg[o + 0], v.x * norm);
        unsafeAtomicAdd(&agg[o + 1], v.y * norm);
        unsafeAtomicAdd(&agg[o + 2], v.z * norm);
        unsafeAtomicAdd(&agg[o + 3], v.w * norm);
    }
}

// ---------------------------------------------------------------- f32 GEMM
// C[M,Nc] = act(opA(A)[M,K] @ B[K,Nc] + biasO). Row-major. BK divides K, BN divides Nc.
template <int BM, int BN, int BK, int TM, int TN, bool RELU_A, bool BIAS_O, bool RELU_O>
__global__ __launch_bounds__(256) void gemm_f32(
    const float* __restrict__ A, const float* __restrict__ B,
    const float* __restrict__ biasO, float* __restrict__ C,
    int M, int K, int Nc) {
    __shared__ float As[BM][BK + 1];   // +1 pad: kill column-read bank conflicts
    __shared__ float Bs[BK][BN];
    const int bm = blockIdx.x * BM;
    const int bn = blockIdx.y * BN;
    constexpr int CT = BN / TN;               // col-groups
    const int tx = threadIdx.x % CT;
    const int ty = threadIdx.x / CT;          // row-groups: (BM/TM)*(BN/TN)==256
    float acc[TM][TN] = {};

    for (int k0 = 0; k0 < K; k0 += BK) {
        constexpr int A_IT = (BM * BK / 4) / 256;
        #pragma unroll
        for (int it = 0; it < A_IT; ++it) {
            int idx = it * 256 + threadIdx.x;
            int r = idx / (BK / 4);
            int c = (idx % (BK / 4)) * 4;
            int gr = bm + r;
            float4 v = make_float4(0.f, 0.f, 0.f, 0.f);
            if (gr < M) v = *(const float4*)&A[(size_t)gr * K + k0 + c];
            if (RELU_A) {
                v.x = fmaxf(v.x, 0.f); v.y = fmaxf(v.y, 0.f);
                v.z = fmaxf(v.z, 0.f); v.w = fmaxf(v.w, 0.f);
            }
            As[r][c + 0] = v.x; As[r][c + 1] = v.y;
            As[r][c + 2] = v.z; As[r][c + 3] = v.w;
        }
        constexpr int B_IT = (BK * BN / 4) / 256;
        #pragma unroll
        for (int it = 0; it < B_IT; ++it) {
            int idx = it * 256 + threadIdx.x;
            int r = idx / (BN / 4);
            int c = (idx % (BN / 4)) * 4;
            *(float4*)&Bs[r][c] = *(const float4*)&B[(size_t)(k0 + r) * Nc + bn + c];
        }
        __syncthreads();
        #pragma unroll
        for (int kk = 0; kk < BK; ++kk) {
            float a[TM], b[TN];
            #pragma unroll
            for (int j = 0; j < TM; ++j) a[j] = As[ty * TM + j][kk];
            #pragma unroll
            for (int i = 0; i < TN; ++i) b[i] = Bs[kk][tx * TN + i];
            #pragma unroll
            for (int j = 0; j < TM; ++j)
                #pragma unroll
                for (int i = 0; i < TN; ++i)
                    acc[j][i] = fmaf(a[j], b[i], acc[j][i]);
        }
        __syncthreads();
    }
    #pragma unroll
    for (int j = 0; j < TM; ++j) {
        int gr = bm + ty * TM + j;
        if (gr >= M) continue;
        #pragma unroll
        for (int i = 0; i < TN; i += 4) {
            int gc = bn + tx * TN + i;
            float4 v = make_float4(acc[j][i], acc[j][i + 1], acc[j][i + 2], acc[j][i + 3]);
            if (BIAS_O) {
                v.x += biasO[gc]; v.y += biasO[gc + 1];
                v.z += biasO[gc + 2]; v.w += biasO[gc + 3];
            }
            if (RELU_O) {
                v.x = fmaxf(v.x, 0.f); v.y = fmaxf(v.y, 0.f);
                v.z = fmaxf(v.z, 0.f); v.w = fmaxf(v.w, 0.f);
            }
            *(float4*)&C[(size_t)gr * Nc + gc] = v;
        }
    }
}

// ---------------------------------------------------------------- launch
extern "C" void kernel_launch(void* const* d_in, const int* in_sizes, int n_in,
                              void* d_out, int out_size, void* d_ws, size_t ws_size,
                              hipStream_t stream) {
    const float* x      = (const float*)d_in[0];
    const int*   edge   = (const int*)d_in[1];     // [2,E]: src = edge, dst = edge+E
    const float* W_conv = (const float*)d_in[2];
    const float* b_conv = (const float*)d_in[3];
    const float* W_lin  = (const float*)d_in[4];
    const float* b_lin  = (const float*)d_in[5];
    const float* W_dec1 = (const float*)d_in[6];
    const float* b_dec1 = (const float*)d_in[7];
    const float* W_dec2 = (const float*)d_in[8];
    const float* b_dec2 = (const float*)d_in[9];
    float* out = (float*)d_out;

    const int Nn = in_sizes[0] / N_DIM;    // 100000
    const int E  = in_sizes[1] / 2;        // 1600000
    const int* src = edge;
    const int* dst = edge + E;

    // workspace layout (floats): h[N*128] | agg[N*128] | dis[N] | z[N*64]; d reuses h
    float* h   = (float*)d_ws;
    float* agg = h + (size_t)Nn * H0;
    float* dis = agg + (size_t)Nn * H0;
    float* z   = dis + Nn;
    float* dbuf = h;   // h dead after GEMM2

    // 1. deg
    fill_deg<<<(Nn + 255) / 256, 256, 0, stream>>>(dis, Nn);
    count_deg<<<4096, 256, 0, stream>>>(dst, dis, E);
    // 2. h = x @ W_conv   [100000,256]x[256,128]
    gemm_f32<64, 128, 32, 4, 8, false, false, false>
        <<<dim3((Nn + 63) / 64, 1), 256, 0, stream>>>(x, W_conv, nullptr, h, Nn, N_DIM, H0);
    // 3. dis = rsqrt(deg); agg = h*dis^2 + b_conv
    finalize_dis_init_agg<<<(Nn * 32 + 255) / 256, 256, 0, stream>>>(dis, h, b_conv, agg, Nn);
    // 4. scatter-add over edges
    scatter_edges<<<8192, 256, 0, stream>>>(src, dst, dis, h, agg, E);
    // 5. z = relu(agg) @ W_lin + b_lin   [.,128]x[128,64]
    gemm_f32<64, 64, 32, 4, 4, true, true, false>
        <<<dim3((Nn + 63) / 64, 1), 256, 0, stream>>>(agg, W_lin, b_lin, z, Nn, H0, H1);
    // 6. d = relu(z @ W_dec1 + b_dec1)   [.,64]x[64,128]
    gemm_f32<64, 128, 32, 4, 8, false, true, true>
        <<<dim3((Nn + 63) / 64, 1), 256, 0, stream>>>(z, W_dec1, b_dec1, dbuf, Nn, H1, H0);
    // 7. out = d @ W_dec2 + b_dec2       [.,128]x[128,256]
    gemm_f32<64, 128, 32, 4, 8, false, true, false>
        <<<dim3((Nn + 63) / 64, 2), 256, 0, stream>>>(dbuf, W_dec2, b_dec2, out, Nn, H0, N_DIM);
}

// Round 3
// 673.075 us; speedup vs baseline: 4.7414x; 4.7414x over previous
//
#include <hip/hip_runtime.h>
#include <hip/hip_bf16.h>

// GCN autoencoder: h=x@Wc; agg = D^-1/2 (A+I) D^-1/2 h + bc; relu;
// z=h@Wl+bl; d=relu(z@Wd1+bd1); out=d@Wd2+bd2.
// N=100000, E=1600000, D=256, H0=128, H1=64.
// R2 (resubmit; R2 bench was GPUAcquisitionTimeout): scatter-atomics
// (204.8M f32 atomics, 3.28 GB WRITE_SIZE) replaced by device-built CSR +
// register-accumulating gather (1 write per output row).

#define N_DIM 256
#define H0 128
#define H1 64

// ---------------------------------------------------------------- CSR build
__global__ __launch_bounds__(256) void zero_int(int* __restrict__ p, int n) {
    int i = blockIdx.x * 256 + threadIdx.x;
    if (i < n) p[i] = 0;
}

__global__ __launch_bounds__(256) void hist_dst(const int* __restrict__ dst,
                                                int* __restrict__ cnt, int E) {
    int e = blockIdx.x * 256 + threadIdx.x;
    if (e < E) atomicAdd(&cnt[dst[e]], 1);
}

// exclusive scan, stage A: per-block scan of 256 + block totals
__global__ __launch_bounds__(256) void scanA(const int* __restrict__ cnt,
                                             int* __restrict__ row_ptr,
                                             int* __restrict__ blockSum, int n) {
    __shared__ int tmp[256];
    int i = blockIdx.x * 256 + threadIdx.x;
    int v = (i < n) ? cnt[i] : 0;
    tmp[threadIdx.x] = v;
    __syncthreads();
    #pragma unroll
    for (int off = 1; off < 256; off <<= 1) {
        int t = (threadIdx.x >= (unsigned)off) ? tmp[threadIdx.x - off] : 0;
        __syncthreads();
        tmp[threadIdx.x] += t;
        __syncthreads();
    }
    if (i < n) row_ptr[i] = tmp[threadIdx.x] - v;     // exclusive
    if (threadIdx.x == 255) blockSum[blockIdx.x] = tmp[255];
}

// stage B: single-block exclusive scan over block totals (nb <= 1024)
__global__ __launch_bounds__(1024) void scanB(int* __restrict__ blockSum, int nb) {
    __shared__ int tmp[1024];
    int v = ((int)threadIdx.x < nb) ? blockSum[threadIdx.x] : 0;
    tmp[threadIdx.x] = v;
    __syncthreads();
    #pragma unroll
    for (int off = 1; off < 1024; off <<= 1) {
        int t = (threadIdx.x >= (unsigned)off) ? tmp[threadIdx.x - off] : 0;
        __syncthreads();
        tmp[threadIdx.x] += t;
        __syncthreads();
    }
    if ((int)threadIdx.x < nb) blockSum[threadIdx.x] = tmp[threadIdx.x] - v;
}

// stage C: add block offsets, init write cursors, cap row_ptr[n]
__global__ __launch_bounds__(256) void scanC(int* __restrict__ row_ptr,
                                             const int* __restrict__ blockSum,
                                             int* __restrict__ cursor, int n, int E) {
    int i = blockIdx.x * 256 + threadIdx.x;
    if (i < n) {
        int v = row_ptr[i] + blockSum[blockIdx.x];
        row_ptr[i] = v;
        cursor[i] = v;
    }
    if (i == 0) row_ptr[n] = E;
}

__global__ __launch_bounds__(256) void finalize_dis(const int* __restrict__ cnt,
                                                    float* __restrict__ dis, int n) {
    int i = blockIdx.x * 256 + threadIdx.x;
    if (i < n) dis[i] = rsqrtf((float)cnt[i] + 1.0f);   // +1 self-loop; deg>=1
}

// one int atomic per edge; store (src, norm) packed 8B for one broadcast load
__global__ __launch_bounds__(256) void build_csr(const int* __restrict__ src,
                                                 const int* __restrict__ dst,
                                                 const float* __restrict__ dis,
                                                 int* __restrict__ cursor,
                                                 int2* __restrict__ csr, int E) {
    int e = blockIdx.x * 256 + threadIdx.x;
    if (e >= E) return;
    int r = src[e], c = dst[e];
    int pos = atomicAdd(&cursor[c], 1);
    csr[pos] = make_int2(r, __float_as_int(dis[r] * dis[c]));
}

// ---------------------------------------------------------------- gather
// agg[c][:] = h[c]*dis[c]^2 + b_conv + sum_{(r,c) in E} h[r]*norm. 32 lanes/node.
__global__ __launch_bounds__(256) void gather_nodes(
    const int* __restrict__ row_ptr, const int2* __restrict__ csr,
    const float* __restrict__ dis, const float* __restrict__ h,
    const float* __restrict__ b_conv, float* __restrict__ agg, int n) {
    int gid  = (blockIdx.x * 256 + threadIdx.x) >> 5;
    int lane = threadIdx.x & 31;
    if (gid >= n) return;
    int beg = row_ptr[gid], end = row_ptr[gid + 1];
    float dc = dis[gid];
    float s  = dc * dc;
    const int lo = lane * 4;
    float4 hv = *(const float4*)&h[(size_t)gid * H0 + lo];
    float4 bv = *(const float4*)&b_conv[lo];
    float ax = fmaf(hv.x, s, bv.x), ay = fmaf(hv.y, s, bv.y);
    float az = fmaf(hv.z, s, bv.z), aw = fmaf(hv.w, s, bv.w);
    int j = beg;
    for (; j + 2 <= end; j += 2) {        // 2 edges in flight for MLP
        int2 e0 = csr[j], e1 = csr[j + 1];
        float4 v0 = *(const float4*)&h[(size_t)e0.x * H0 + lo];
        float4 v1 = *(const float4*)&h[(size_t)e1.x * H0 + lo];
        float n0 = __int_as_float(e0.y), n1 = __int_as_float(e1.y);
        ax = fmaf(v0.x, n0, ax); ay = fmaf(v0.y, n0, ay);
        az = fmaf(v0.z, n0, az); aw = fmaf(v0.w, n0, aw);
        ax = fmaf(v1.x, n1, ax); ay = fmaf(v1.y, n1, ay);
        az = fmaf(v1.z, n1, az); aw = fmaf(v1.w, n1, aw);
    }
    if (j < end) {
        int2 e0 = csr[j];
        float4 v0 = *(const float4*)&h[(size_t)e0.x * H0 + lo];
        float n0 = __int_as_float(e0.y);
        ax = fmaf(v0.x, n0, ax); ay = fmaf(v0.y, n0, ay);
        az = fmaf(v0.z, n0, az); aw = fmaf(v0.w, n0, aw);
    }
    *(float4*)&agg[(size_t)gid * H0 + lo] = make_float4(ax, ay, az, aw);
}

// ---------------------------------------------------------------- f32 GEMM
// C[M,Nc] = act(opA(A)[M,K] @ B[K,Nc] + biasO). Row-major. BK|K, BN|Nc.
template <int BM, int BN, int BK, int TM, int TN, bool RELU_A, bool BIAS_O, bool RELU_O>
__global__ __launch_bounds__(256) void gemm_f32(
    const float* __restrict__ A, const float* __restrict__ B,
    const float* __restrict__ biasO, float* __restrict__ C,
    int M, int K, int Nc) {
    __shared__ float As[BM][BK + 1];
    __shared__ float Bs[BK][BN];
    const int bm = blockIdx.x * BM;
    const int bn = blockIdx.y * BN;
    constexpr int CT = BN / TN;
    const int tx = threadIdx.x % CT;
    const int ty = threadIdx.x / CT;
    float acc[TM][TN] = {};

    for (int k0 = 0; k0 < K; k0 += BK) {
        constexpr int A_IT = (BM * BK / 4) / 256;
        #pragma unroll
        for (int it = 0; it < A_IT; ++it) {
            int idx = it * 256 + threadIdx.x;
            int r = idx / (BK / 4);
            int c = (idx % (BK / 4)) * 4;
            int gr = bm + r;
            float4 v = make_float4(0.f, 0.f, 0.f, 0.f);
            if (gr < M) v = *(const float4*)&A[(size_t)gr * K + k0 + c];
            if (RELU_A) {
                v.x = fmaxf(v.x, 0.f); v.y = fmaxf(v.y, 0.f);
                v.z = fmaxf(v.z, 0.f); v.w = fmaxf(v.w, 0.f);
            }
            As[r][c + 0] = v.x; As[r][c + 1] = v.y;
            As[r][c + 2] = v.z; As[r][c + 3] = v.w;
        }
        constexpr int B_IT = (BK * BN / 4) / 256;
        #pragma unroll
        for (int it = 0; it < B_IT; ++it) {
            int idx = it * 256 + threadIdx.x;
            int r = idx / (BN / 4);
            int c = (idx % (BN / 4)) * 4;
            *(float4*)&Bs[r][c] = *(const float4*)&B[(size_t)(k0 + r) * Nc + bn + c];
        }
        __syncthreads();
        #pragma unroll
        for (int kk = 0; kk < BK; ++kk) {
            float a[TM], b[TN];
            #pragma unroll
            for (int j = 0; j < TM; ++j) a[j] = As[ty * TM + j][kk];
            #pragma unroll
            for (int i = 0; i < TN; ++i) b[i] = Bs[kk][tx * TN + i];
            #pragma unroll
            for (int j = 0; j < TM; ++j)
                #pragma unroll
                for (int i = 0; i < TN; ++i)
                    acc[j][i] = fmaf(a[j], b[i], acc[j][i]);
        }
        __syncthreads();
    }
    #pragma unroll
    for (int j = 0; j < TM; ++j) {
        int gr = bm + ty * TM + j;
        if (gr >= M) continue;
        #pragma unroll
        for (int i = 0; i < TN; i += 4) {
            int gc = bn + tx * TN + i;
            float4 v = make_float4(acc[j][i], acc[j][i + 1], acc[j][i + 2], acc[j][i + 3]);
            if (BIAS_O) {
                v.x += biasO[gc]; v.y += biasO[gc + 1];
                v.z += biasO[gc + 2]; v.w += biasO[gc + 3];
            }
            if (RELU_O) {
                v.x = fmaxf(v.x, 0.f); v.y = fmaxf(v.y, 0.f);
                v.z = fmaxf(v.z, 0.f); v.w = fmaxf(v.w, 0.f);
            }
            *(float4*)&C[(size_t)gr * Nc + gc] = v;
        }
    }
}

// ---------------------------------------------------------------- launch
extern "C" void kernel_launch(void* const* d_in, const int* in_sizes, int n_in,
                              void* d_out, int out_size, void* d_ws, size_t ws_size,
                              hipStream_t stream) {
    const float* x      = (const float*)d_in[0];
    const int*   edge   = (const int*)d_in[1];     // [2,E]: src = edge, dst = edge+E
    const float* W_conv = (const float*)d_in[2];
    const float* b_conv = (const float*)d_in[3];
    const float* W_lin  = (const float*)d_in[4];
    const float* b_lin  = (const float*)d_in[5];
    const float* W_dec1 = (const float*)d_in[6];
    const float* b_dec1 = (const float*)d_in[7];
    const float* W_dec2 = (const float*)d_in[8];
    const float* b_dec2 = (const float*)d_in[9];
    float* out = (float*)d_out;

    const int Nn = in_sizes[0] / N_DIM;    // 100000
    const int E  = in_sizes[1] / 2;        // 1600000
    const int* src = edge;
    const int* dst = edge + E;

    // ws layout (floats): h[N*H0] | agg[N*H0] | z-region[N*H1 + slack]
    // CSR scratch overlays the z region (dead until GEMM2); dbuf reuses h.
    float* h    = (float*)d_ws;
    float* agg  = h + (size_t)Nn * H0;
    float* zr   = agg + (size_t)Nn * H0;
    float* z    = zr;
    int2*  csr      = (int2*)zr;                       // E entries (2E words)
    int*   cursor   = (int*)zr + 2 * (size_t)E;        // N
    int*   row_ptr  = cursor + Nn;                     // N+1
    int*   cnt      = row_ptr + Nn + 1;                // N
    float* dis      = (float*)(cnt + Nn);              // N
    int*   blockSum = (int*)(dis + Nn);                // nb
    float* dbuf = h;

    const int nb = (Nn + 255) / 256;

    // 1. degree histogram + exclusive scan -> row_ptr/cursor; dis = rsqrt(deg)
    zero_int<<<nb, 256, 0, stream>>>(cnt, Nn);
    hist_dst<<<(E + 255) / 256, 256, 0, stream>>>(dst, cnt, E);
    scanA<<<nb, 256, 0, stream>>>(cnt, row_ptr, blockSum, Nn);
    scanB<<<1, 1024, 0, stream>>>(blockSum, nb);
    scanC<<<nb, 256, 0, stream>>>(row_ptr, blockSum, cursor, Nn, E);
    finalize_dis<<<nb, 256, 0, stream>>>(cnt, dis, Nn);
    // 2. h = x @ W_conv   [100000,256]x[256,128]
    gemm_f32<64, 128, 32, 4, 8, false, false, false>
        <<<dim3((Nn + 63) / 64, 1), 256, 0, stream>>>(x, W_conv, nullptr, h, Nn, N_DIM, H0);
    // 3. CSR edge lists (1 int atomic per edge)
    build_csr<<<(E + 255) / 256, 256, 0, stream>>>(src, dst, dis, cursor, csr, E);
    // 4. gather: agg = self + neighbors + bias (single write per row)
    gather_nodes<<<((size_t)Nn * 32 + 255) / 256, 256, 0, stream>>>(
        row_ptr, csr, dis, h, b_conv, agg, Nn);
    // 5. z = relu(agg) @ W_lin + b_lin   [.,128]x[128,64]
    gemm_f32<64, 64, 32, 4, 4, true, true, false>
        <<<dim3((Nn + 63) / 64, 1), 256, 0, stream>>>(agg, W_lin, b_lin, z, Nn, H0, H1);
    // 6. d = relu(z @ W_dec1 + b_dec1)   [.,64]x[64,128]
    gemm_f32<64, 128, 32, 4, 8, false, true, true>
        <<<dim3((Nn + 63) / 64, 1), 256, 0, stream>>>(z, W_dec1, b_dec1, dbuf, Nn, H1, H0);
    // 7. out = d @ W_dec2 + b_dec2       [.,128]x[128,256]
    gemm_f32<64, 128, 32, 4, 8, false, true, false>
        <<<dim3((Nn + 63) / 64, 2), 256, 0, stream>>>(dbuf, W_dec2, b_dec2, out, Nn, H0, N_DIM);
}

// Round 4
// 597.483 us; speedup vs baseline: 5.3412x; 1.1265x over previous
//
#include <hip/hip_runtime.h>
#include <hip/hip_bf16.h>

// GCN autoencoder. N=100000, E=1600000, D=256, H0=128, H1=64.
// R4: (1) all four GEMMs -> bf16 MFMA (32x32x16) with hi/lo split-precision
//     (3 MFMA terms ~ f32 accuracy); GEMMs become memory-bound (~25 us floor).
// (2) GEMM1 emits h as bf16 hi/lo planes; gather reads neighbors hi-only
//     (halves gather FETCH), self-term reads hi+lo (full precision).

#define N_DIM 256
#define H0 128
#define H1 64

typedef __bf16 bf16x8 __attribute__((ext_vector_type(8)));
typedef short  short8 __attribute__((ext_vector_type(8)));
typedef short  s16x4  __attribute__((ext_vector_type(4)));
typedef float  f32x16 __attribute__((ext_vector_type(16)));

// round-to-nearest-even f32 -> bf16 bits (finite data only)
__device__ inline unsigned bf_hi(float v) {
    unsigned b = __float_as_uint(v);
    return (b + 0x7FFF + ((b >> 16) & 1)) >> 16;
}
__device__ inline float bf_f(unsigned bits) { return __uint_as_float(bits << 16); }

// ---------------------------------------------------------------- CSR build
__global__ __launch_bounds__(256) void zero_int(int* __restrict__ p, int n) {
    int i = blockIdx.x * 256 + threadIdx.x;
    if (i < n) p[i] = 0;
}

__global__ __launch_bounds__(256) void hist_dst(const int* __restrict__ dst,
                                                int* __restrict__ cnt, int E) {
    int e = blockIdx.x * 256 + threadIdx.x;
    if (e < E) atomicAdd(&cnt[dst[e]], 1);
}

__global__ __launch_bounds__(256) void scanA(const int* __restrict__ cnt,
                                             int* __restrict__ row_ptr,
                                             int* __restrict__ blockSum, int n) {
    __shared__ int tmp[256];
    int i = blockIdx.x * 256 + threadIdx.x;
    int v = (i < n) ? cnt[i] : 0;
    tmp[threadIdx.x] = v;
    __syncthreads();
    #pragma unroll
    for (int off = 1; off < 256; off <<= 1) {
        int t = (threadIdx.x >= (unsigned)off) ? tmp[threadIdx.x - off] : 0;
        __syncthreads();
        tmp[threadIdx.x] += t;
        __syncthreads();
    }
    if (i < n) row_ptr[i] = tmp[threadIdx.x] - v;
    if (threadIdx.x == 255) blockSum[blockIdx.x] = tmp[255];
}

__global__ __launch_bounds__(1024) void scanB(int* __restrict__ blockSum, int nb) {
    __shared__ int tmp[1024];
    int v = ((int)threadIdx.x < nb) ? blockSum[threadIdx.x] : 0;
    tmp[threadIdx.x] = v;
    __syncthreads();
    #pragma unroll
    for (int off = 1; off < 1024; off <<= 1) {
        int t = (threadIdx.x >= (unsigned)off) ? tmp[threadIdx.x - off] : 0;
        __syncthreads();
        tmp[threadIdx.x] += t;
        __syncthreads();
    }
    if ((int)threadIdx.x < nb) blockSum[threadIdx.x] = tmp[threadIdx.x] - v;
}

__global__ __launch_bounds__(256) void scanC(int* __restrict__ row_ptr,
                                             const int* __restrict__ blockSum,
                                             int* __restrict__ cursor, int n, int E) {
    int i = blockIdx.x * 256 + threadIdx.x;
    if (i < n) {
        int v = row_ptr[i] + blockSum[blockIdx.x];
        row_ptr[i] = v;
        cursor[i] = v;
    }
    if (i == 0) row_ptr[n] = E;
}

__global__ __launch_bounds__(256) void finalize_dis(const int* __restrict__ cnt,
                                                    float* __restrict__ dis, int n) {
    int i = blockIdx.x * 256 + threadIdx.x;
    if (i < n) dis[i] = rsqrtf((float)cnt[i] + 1.0f);
}

__global__ __launch_bounds__(256) void build_csr(const int* __restrict__ src,
                                                 const int* __restrict__ dst,
                                                 const float* __restrict__ dis,
                                                 int* __restrict__ cursor,
                                                 int2* __restrict__ csr, int E) {
    int e = blockIdx.x * 256 + threadIdx.x;
    if (e >= E) return;
    int r = src[e], c = dst[e];
    int pos = atomicAdd(&cursor[c], 1);
    csr[pos] = make_int2(r, __float_as_int(dis[r] * dis[c]));
}

// ---------------------------------------------------------------- gather
// agg[c] = (hi+lo)(h[c])*dis^2 + b_conv + sum_edges hi(h[r])*norm. 32 lanes/node.
__global__ __launch_bounds__(256) void gather_nodes(
    const int* __restrict__ row_ptr, const int2* __restrict__ csr,
    const float* __restrict__ dis, const unsigned short* __restrict__ hb,
    const float* __restrict__ b_conv, float* __restrict__ agg, int n) {
    int gid  = (blockIdx.x * 256 + threadIdx.x) >> 5;
    int lane = threadIdx.x & 31;
    if (gid >= n) return;
    const size_t loOff = (size_t)n * H0;
    int beg = row_ptr[gid], end = row_ptr[gid + 1];
    float dc = dis[gid];
    float s  = dc * dc;
    const int lo4 = lane * 4;
    ushort4 sh = *(const ushort4*)&hb[(size_t)gid * H0 + lo4];
    ushort4 sl = *(const ushort4*)&hb[loOff + (size_t)gid * H0 + lo4];
    float4 bv = *(const float4*)&b_conv[lo4];
    float ax = fmaf(bf_f(sh.x) + bf_f(sl.x), s, bv.x);
    float ay = fmaf(bf_f(sh.y) + bf_f(sl.y), s, bv.y);
    float az = fmaf(bf_f(sh.z) + bf_f(sl.z), s, bv.z);
    float aw = fmaf(bf_f(sh.w) + bf_f(sl.w), s, bv.w);
    int j = beg;
    for (; j + 2 <= end; j += 2) {
        int2 e0 = csr[j], e1 = csr[j + 1];
        ushort4 v0 = *(const ushort4*)&hb[(size_t)e0.x * H0 + lo4];
        ushort4 v1 = *(const ushort4*)&hb[(size_t)e1.x * H0 + lo4];
        float n0 = __int_as_float(e0.y), n1 = __int_as_float(e1.y);
        ax = fmaf(bf_f(v0.x), n0, ax); ay = fmaf(bf_f(v0.y), n0, ay);
        az = fmaf(bf_f(v0.z), n0, az); aw = fmaf(bf_f(v0.w), n0, aw);
        ax = fmaf(bf_f(v1.x), n1, ax); ay = fmaf(bf_f(v1.y), n1, ay);
        az = fmaf(bf_f(v1.z), n1, az); aw = fmaf(bf_f(v1.w), n1, aw);
    }
    if (j < end) {
        int2 e0 = csr[j];
        ushort4 v0 = *(const ushort4*)&hb[(size_t)e0.x * H0 + lo4];
        float n0 = __int_as_float(e0.y);
        ax = fmaf(bf_f(v0.x), n0, ax); ay = fmaf(bf_f(v0.y), n0, ay);
        az = fmaf(bf_f(v0.z), n0, az); aw = fmaf(bf_f(v0.w), n0, aw);
    }
    *(float4*)&agg[(size_t)gid * H0 + lo4] = make_float4(ax, ay, az, aw);
}

// ---------------------------------------------------------------- MFMA GEMM
// C[M,Nc] = act(opA(A) @ B + bias), split-precision bf16 MFMA (3 terms).
// BM=128 rows, BN in {64,128}, BK=32. 256 threads = 4 waves (2x2), wave tile
// 64 x (BN/2), frags 32x32. LDS: A/B hi+lo bf16 planes (stride 40 = pad, bank-
// spread + 16B-aligned) + f32 bounce buffer for B-transpose (stride BN+4).
template <int BM, int BN, int BK, int RELU_A, int BIAS, int RELU_O, int OUT_SPLIT>
__global__ __launch_bounds__(256) void gemm_mfma(
    const float* __restrict__ A, const float* __restrict__ B,
    const float* __restrict__ bias, float* __restrict__ C,
    unsigned short* __restrict__ Cs, int M, int K, int Nc) {
    constexpr int WN  = BN / 2;    // wave n-extent
    constexpr int FNv = WN / 32;   // 32x32 frags per wave in n
    constexpr int LSA = 40;        // bf16 LDS row stride (BK=32 + 8 pad)
    constexpr int BS  = BN + 4;    // f32 bounce row stride

    __shared__ short Ah[BM * LSA], Al[BM * LSA];
    __shared__ short Bh[BN * LSA], Bl[BN * LSA];
    __shared__ float Bs32[BK * BS];

    const int tid  = threadIdx.x;
    const int lane = tid & 63, wid = tid >> 6;
    const int wm = wid >> 1, wn = wid & 1;
    const int l31 = lane & 31, l5 = lane >> 5;
    const int bm = blockIdx.x * BM;
    const int bn = blockIdx.y * BN;

    f32x16 acc[2][FNv] = {};

    for (int k0 = 0; k0 < K; k0 += BK) {
        // ---- stage A (split f32 -> hi/lo bf16) ----
        #pragma unroll
        for (int it = 0; it < (BM * BK) / (4 * 256); ++it) {
            int u = it * 256 + tid;
            int r = u >> 3, c4 = u & 7;
            int gr = bm + r;
            float4 v = make_float4(0.f, 0.f, 0.f, 0.f);
            if (gr < M) v = *(const float4*)&A[(size_t)gr * K + k0 + c4 * 4];
            if (RELU_A) {
                v.x = fmaxf(v.x, 0.f); v.y = fmaxf(v.y, 0.f);
                v.z = fmaxf(v.z, 0.f); v.w = fmaxf(v.w, 0.f);
            }
            s16x4 hi4, lo4;
            float f[4] = {v.x, v.y, v.z, v.w};
            #pragma unroll
            for (int i = 0; i < 4; ++i) {
                unsigned hb_ = bf_hi(f[i]);
                hi4[i] = (short)hb_;
                lo4[i] = (short)bf_hi(f[i] - bf_f(hb_));
            }
            *(s16x4*)&Ah[r * LSA + c4 * 4] = hi4;
            *(s16x4*)&Al[r * LSA + c4 * 4] = lo4;
        }
        // ---- stage B tile (f32, coalesced) into bounce buffer ----
        #pragma unroll
        for (int it = 0; it < (BK * BN) / (4 * 256); ++it) {
            int u = it * 256 + tid;
            int rB = u / (BN / 4), c4 = u % (BN / 4);
            *(float4*)&Bs32[rB * BS + c4 * 4] =
                *(const float4*)&B[(size_t)(k0 + rB) * Nc + bn + c4 * 4];
        }
        __syncthreads();
        // ---- transpose + split B: Bh/Bl[n][k] ----
        #pragma unroll
        for (int it = 0; it < BN / 32; ++it) {
            int rq = tid & 7;              // k quad
            int c  = (tid >> 3) + it * 32; // n col
            s16x4 hi4, lo4;
            #pragma unroll
            for (int i = 0; i < 4; ++i) {
                float v = Bs32[(rq * 4 + i) * BS + c];
                unsigned hb_ = bf_hi(v);
                hi4[i] = (short)hb_;
                lo4[i] = (short)bf_hi(v - bf_f(hb_));
            }
            *(s16x4*)&Bh[c * LSA + rq * 4] = hi4;
            *(s16x4*)&Bl[c * LSA + rq * 4] = lo4;
        }
        __syncthreads();
        // ---- fragments + MFMA (two k-halves of 16) ----
        #pragma unroll
        for (int kh = 0; kh < 2; ++kh) {
            const int kcol = kh * 16 + l5 * 8;
            bf16x8 ah[2], al[2], bh[FNv], bl[FNv];
            #pragma unroll
            for (int fm = 0; fm < 2; ++fm) {
                int row = wm * 64 + fm * 32 + l31;
                ah[fm] = __builtin_bit_cast(bf16x8, *(const short8*)&Ah[row * LSA + kcol]);
                al[fm] = __builtin_bit_cast(bf16x8, *(const short8*)&Al[row * LSA + kcol]);
            }
            #pragma unroll
            for (int fn = 0; fn < FNv; ++fn) {
                int col = wn * WN + fn * 32 + l31;
                bh[fn] = __builtin_bit_cast(bf16x8, *(const short8*)&Bh[col * LSA + kcol]);
                bl[fn] = __builtin_bit_cast(bf16x8, *(const short8*)&Bl[col * LSA + kcol]);
            }
            #pragma unroll
            for (int fm = 0; fm < 2; ++fm)
                #pragma unroll
                for (int fn = 0; fn < FNv; ++fn) {
                    acc[fm][fn] = __builtin_amdgcn_mfma_f32_32x32x16_bf16(
                        al[fm], bh[fn], acc[fm][fn], 0, 0, 0);
                    acc[fm][fn] = __builtin_amdgcn_mfma_f32_32x32x16_bf16(
                        ah[fm], bl[fn], acc[fm][fn], 0, 0, 0);
                    acc[fm][fn] = __builtin_amdgcn_mfma_f32_32x32x16_bf16(
                        ah[fm], bh[fn], acc[fm][fn], 0, 0, 0);
                }
        }
        __syncthreads();
    }
    // ---- epilogue: D mapping col=lane&31, row=(j&3)+8*(j>>2)+4*(lane>>5) ----
    const size_t loOff = (size_t)M * Nc;
    #pragma unroll
    for (int fm = 0; fm < 2; ++fm)
        #pragma unroll
        for (int fn = 0; fn < FNv; ++fn) {
            int ncol = bn + wn * WN + fn * 32 + l31;
            float bv = BIAS ? bias[ncol] : 0.f;
            #pragma unroll
            for (int j = 0; j < 16; ++j) {
                int gm = bm + wm * 64 + fm * 32 + (j & 3) + 8 * (j >> 2) + 4 * l5;
                if (gm >= M) continue;
                float v = acc[fm][fn][j] + bv;
                if (RELU_O) v = fmaxf(v, 0.f);
                if (OUT_SPLIT) {
                    unsigned hb_ = bf_hi(v);
                    Cs[(size_t)gm * Nc + ncol] = (unsigned short)hb_;
                    Cs[loOff + (size_t)gm * Nc + ncol] = (unsigned short)bf_hi(v - bf_f(hb_));
                } else {
                    C[(size_t)gm * Nc + ncol] = v;
                }
            }
        }
}

// ---------------------------------------------------------------- launch
extern "C" void kernel_launch(void* const* d_in, const int* in_sizes, int n_in,
                              void* d_out, int out_size, void* d_ws, size_t ws_size,
                              hipStream_t stream) {
    const float* x      = (const float*)d_in[0];
    const int*   edge   = (const int*)d_in[1];
    const float* W_conv = (const float*)d_in[2];
    const float* b_conv = (const float*)d_in[3];
    const float* W_lin  = (const float*)d_in[4];
    const float* b_lin  = (const float*)d_in[5];
    const float* W_dec1 = (const float*)d_in[6];
    const float* b_dec1 = (const float*)d_in[7];
    const float* W_dec2 = (const float*)d_in[8];
    const float* b_dec2 = (const float*)d_in[9];
    float* out = (float*)d_out;

    const int Nn = in_sizes[0] / N_DIM;    // 100000
    const int E  = in_sizes[1] / 2;        // 1600000
    const int* src = edge;
    const int* dst = edge + E;

    // ws (f32 words): S0 h-slot [N*128]: bf16 hi/lo planes, later d f32.
    // S1 agg f32 [N*128]. S2: csr scratch then z f32 (csr dead after gather).
    float* s0   = (float*)d_ws;
    float* agg  = s0 + (size_t)Nn * H0;
    float* zr   = agg + (size_t)Nn * H0;
    float* z    = zr;
    int2*  csr      = (int2*)zr;
    int*   cursor   = (int*)zr + 2 * (size_t)E;
    int*   row_ptr  = cursor + Nn;
    int*   cnt      = row_ptr + Nn + 1;
    float* dis      = (float*)(cnt + Nn);
    int*   blockSum = (int*)(dis + Nn);
    unsigned short* hb = (unsigned short*)s0;  // hi plane, lo at +Nn*H0
    float* dbuf = s0;                          // d f32 after gather

    const int nb = (Nn + 255) / 256;
    const int gM = (Nn + 127) / 128;           // 782 row-blocks

    // 1. degree + scan + dis
    zero_int<<<nb, 256, 0, stream>>>(cnt, Nn);
    hist_dst<<<(E + 255) / 256, 256, 0, stream>>>(dst, cnt, E);
    scanA<<<nb, 256, 0, stream>>>(cnt, row_ptr, blockSum, Nn);
    scanB<<<1, 1024, 0, stream>>>(blockSum, nb);
    scanC<<<nb, 256, 0, stream>>>(row_ptr, blockSum, cursor, Nn, E);
    finalize_dis<<<nb, 256, 0, stream>>>(cnt, dis, Nn);
    // 2. h = x @ W_conv -> bf16 hi/lo planes
    gemm_mfma<128, 128, 32, 0, 0, 0, 1><<<dim3(gM, 1), 256, 0, stream>>>(
        x, W_conv, nullptr, nullptr, hb, Nn, N_DIM, H0);
    // 3. CSR
    build_csr<<<(E + 255) / 256, 256, 0, stream>>>(src, dst, dis, cursor, csr, E);
    // 4. gather
    gather_nodes<<<((size_t)Nn * 32 + 255) / 256, 256, 0, stream>>>(
        row_ptr, csr, dis, hb, b_conv, agg, Nn);
    // 5. z = relu(agg) @ W_lin + b_lin
    gemm_mfma<128, 64, 32, 1, 1, 0, 0><<<dim3(gM, 1), 256, 0, stream>>>(
        agg, W_lin, b_lin, z, nullptr, Nn, H0, H1);
    // 6. d = relu(z @ W_dec1 + b_dec1)
    gemm_mfma<128, 128, 32, 0, 1, 1, 0><<<dim3(gM, 1), 256, 0, stream>>>(
        z, W_dec1, b_dec1, dbuf, nullptr, Nn, H1, H0);
    // 7. out = d @ W_dec2 + b_dec2
    gemm_mfma<128, 128, 32, 0, 1, 0, 0><<<dim3(gM, 2), 256, 0, stream>>>(
        dbuf, W_dec2, b_dec2, out, nullptr, Nn, H0, N_DIM);
}

// Round 5
// 575.126 us; speedup vs baseline: 5.5489x; 1.0389x over previous
//
#include <hip/hip_runtime.h>
#include <hip/hip_bf16.h>

// GCN autoencoder. N=100000, E=1600000, D=256, H0=128, H1=64.
// R5: GEMM1 was latency-bound (MfmaUtil 7%, occ 15%, 4M LDS conflicts from the
// in-kernel B bounce-transpose; 57.8 KB LDS -> 2 blocks/CU).
//  - pre-split+pre-transpose all weights ONCE to bf16 hi/lo planes [n][k]
//  - producers (gather, GEMM2/3) emit split planes -> A-staging is pure copy
//  - GEMM: no bounce, no transpose, 1 barrier/tile, LDS 40.9 KB (3 blocks/CU)
//  - z overlays h-slot, d overlays ra-slot: peak ws ~117 MB

#define N_DIM 256
#define H0 128
#define H1 64

typedef __bf16 bf16x8 __attribute__((ext_vector_type(8)));
typedef short  short8 __attribute__((ext_vector_type(8)));
typedef short  s16x4  __attribute__((ext_vector_type(4)));
typedef float  f32x16 __attribute__((ext_vector_type(16)));
typedef unsigned short ushort_t;

// round-to-nearest-even f32 -> bf16 bits (finite data only)
__device__ inline unsigned bf_hi(float v) {
    unsigned b = __float_as_uint(v);
    return (b + 0x7FFF + ((b >> 16) & 1)) >> 16;
}
__device__ inline float bf_f(unsigned bits) { return __uint_as_float(bits << 16); }

// ------------------------------------------------- weight prep: W[k][n] -> planes[n][k]
__global__ __launch_bounds__(256) void transpose_split(
    const float* __restrict__ W, ushort_t* __restrict__ hi,
    ushort_t* __restrict__ lo, int K, int N) {
    int idx = blockIdx.x * 256 + threadIdx.x;     // over N*K, k fastest
    if (idx >= N * K) return;
    int n = idx / K, k = idx - n * K;
    float v = W[(size_t)k * N + n];
    unsigned h = bf_hi(v);
    hi[idx] = (ushort_t)h;
    lo[idx] = (ushort_t)bf_hi(v - bf_f(h));
}

// ---------------------------------------------------------------- CSR build
__global__ __launch_bounds__(256) void zero_int(int* __restrict__ p, int n) {
    int i = blockIdx.x * 256 + threadIdx.x;
    if (i < n) p[i] = 0;
}

__global__ __launch_bounds__(256) void hist_dst(const int* __restrict__ dst,
                                                int* __restrict__ cnt, int E) {
    int e = blockIdx.x * 256 + threadIdx.x;
    if (e < E) atomicAdd(&cnt[dst[e]], 1);
}

__global__ __launch_bounds__(256) void scanA(const int* __restrict__ cnt,
                                             int* __restrict__ row_ptr,
                                             int* __restrict__ blockSum, int n) {
    __shared__ int tmp[256];
    int i = blockIdx.x * 256 + threadIdx.x;
    int v = (i < n) ? cnt[i] : 0;
    tmp[threadIdx.x] = v;
    __syncthreads();
    #pragma unroll
    for (int off = 1; off < 256; off <<= 1) {
        int t = (threadIdx.x >= (unsigned)off) ? tmp[threadIdx.x - off] : 0;
        __syncthreads();
        tmp[threadIdx.x] += t;
        __syncthreads();
    }
    if (i < n) row_ptr[i] = tmp[threadIdx.x] - v;
    if (threadIdx.x == 255) blockSum[blockIdx.x] = tmp[255];
}

__global__ __launch_bounds__(1024) void scanB(int* __restrict__ blockSum, int nb) {
    __shared__ int tmp[1024];
    int v = ((int)threadIdx.x < nb) ? blockSum[threadIdx.x] : 0;
    tmp[threadIdx.x] = v;
    __syncthreads();
    #pragma unroll
    for (int off = 1; off < 1024; off <<= 1) {
        int t = (threadIdx.x >= (unsigned)off) ? tmp[threadIdx.x - off] : 0;
        __syncthreads();
        tmp[threadIdx.x] += t;
        __syncthreads();
    }
    if ((int)threadIdx.x < nb) blockSum[threadIdx.x] = tmp[threadIdx.x] - v;
}

// stage C + dis: add block offsets, init cursors, dis = rsqrt(deg)
__global__ __launch_bounds__(256) void scanC(int* __restrict__ row_ptr,
                                             const int* __restrict__ blockSum,
                                             int* __restrict__ cursor,
                                             const int* __restrict__ cnt,
                                             float* __restrict__ dis, int n, int E) {
    int i = blockIdx.x * 256 + threadIdx.x;
    if (i < n) {
        int v = row_ptr[i] + blockSum[blockIdx.x];
        row_ptr[i] = v;
        cursor[i] = v;
        dis[i] = rsqrtf((float)cnt[i] + 1.0f);
    }
    if (i == 0) row_ptr[n] = E;
}

__global__ __launch_bounds__(256) void build_csr(const int* __restrict__ src,
                                                 const int* __restrict__ dst,
                                                 const float* __restrict__ dis,
                                                 int* __restrict__ cursor,
                                                 int2* __restrict__ csr, int E) {
    int e = blockIdx.x * 256 + threadIdx.x;
    if (e >= E) return;
    int r = src[e], c = dst[e];
    int pos = atomicAdd(&cursor[c], 1);
    csr[pos] = make_int2(r, __float_as_int(dis[r] * dis[c]));
}

// ---------------------------------------------------------------- gather
// ra[c] = relu( (hi+lo)(h[c])*dis^2 + b_conv + sum_edges hi(h[r])*norm ), split.
__global__ __launch_bounds__(256) void gather_nodes(
    const int* __restrict__ row_ptr, const int2* __restrict__ csr,
    const float* __restrict__ dis, const ushort_t* __restrict__ hb,
    const float* __restrict__ b_conv, ushort_t* __restrict__ ra, int n) {
    int gid  = (blockIdx.x * 256 + threadIdx.x) >> 5;
    int lane = threadIdx.x & 31;
    if (gid >= n) return;
    const size_t loOff = (size_t)n * H0;
    int beg = row_ptr[gid], end = row_ptr[gid + 1];
    float dc = dis[gid];
    float s  = dc * dc;
    const int lo4 = lane * 4;
    ushort4 sh = *(const ushort4*)&hb[(size_t)gid * H0 + lo4];
    ushort4 sl = *(const ushort4*)&hb[loOff + (size_t)gid * H0 + lo4];
    float4 bv = *(const float4*)&b_conv[lo4];
    float ax = fmaf(bf_f(sh.x) + bf_f(sl.x), s, bv.x);
    float ay = fmaf(bf_f(sh.y) + bf_f(sl.y), s, bv.y);
    float az = fmaf(bf_f(sh.z) + bf_f(sl.z), s, bv.z);
    float aw = fmaf(bf_f(sh.w) + bf_f(sl.w), s, bv.w);
    int j = beg;
    for (; j + 2 <= end; j += 2) {
        int2 e0 = csr[j], e1 = csr[j + 1];
        ushort4 v0 = *(const ushort4*)&hb[(size_t)e0.x * H0 + lo4];
        ushort4 v1 = *(const ushort4*)&hb[(size_t)e1.x * H0 + lo4];
        float n0 = __int_as_float(e0.y), n1 = __int_as_float(e1.y);
        ax = fmaf(bf_f(v0.x), n0, ax); ay = fmaf(bf_f(v0.y), n0, ay);
        az = fmaf(bf_f(v0.z), n0, az); aw = fmaf(bf_f(v0.w), n0, aw);
        ax = fmaf(bf_f(v1.x), n1, ax); ay = fmaf(bf_f(v1.y), n1, ay);
        az = fmaf(bf_f(v1.z), n1, az); aw = fmaf(bf_f(v1.w), n1, aw);
    }
    if (j < end) {
        int2 e0 = csr[j];
        ushort4 v0 = *(const ushort4*)&hb[(size_t)e0.x * H0 + lo4];
        float n0 = __int_as_float(e0.y);
        ax = fmaf(bf_f(v0.x), n0, ax); ay = fmaf(bf_f(v0.y), n0, ay);
        az = fmaf(bf_f(v0.z), n0, az); aw = fmaf(bf_f(v0.w), n0, aw);
    }
    // relu + split
    ax = fmaxf(ax, 0.f); ay = fmaxf(ay, 0.f);
    az = fmaxf(az, 0.f); aw = fmaxf(aw, 0.f);
    ushort4 h4, l4;
    unsigned t;
    t = bf_hi(ax); h4.x = t; l4.x = (ushort_t)bf_hi(ax - bf_f(t));
    t = bf_hi(ay); h4.y = t; l4.y = (ushort_t)bf_hi(ay - bf_f(t));
    t = bf_hi(az); h4.z = t; l4.z = (ushort_t)bf_hi(az - bf_f(t));
    t = bf_hi(aw); h4.w = t; l4.w = (ushort_t)bf_hi(aw - bf_f(t));
    *(ushort4*)&ra[(size_t)gid * H0 + lo4] = h4;
    *(ushort4*)&ra[loOff + (size_t)gid * H0 + lo4] = l4;
}

// ---------------------------------------------------------------- MFMA GEMM
// C[M,Nc] = act(A @ B + bias). A: f32 [M][K] (A_SPLIT=0, split in-kernel) or
// pre-split bf16 planes [M][K] hi, lo at +M*K (A_SPLIT=1). B: pre-split
// pre-transposed planes [Nc][K], lo at +Nc*K. 3-term split MFMA (~f32 acc).
// 256 thr = 4 waves (2x2); wave tile 64 x (BN/2); 32x32x16 frags.
template <int BM, int BN, int BK, int A_SPLIT, int BIAS, int RELU_O, int OUT_SPLIT>
__global__ __launch_bounds__(256) void gemm_mfma(
    const float* __restrict__ A, const ushort_t* __restrict__ Asp,
    const ushort_t* __restrict__ Bt, const float* __restrict__ bias,
    float* __restrict__ C, ushort_t* __restrict__ Cs, int M, int K, int Nc) {
    constexpr int WN  = BN / 2;
    constexpr int FNv = WN / 32;
    constexpr int LSA = 40;        // bf16 row stride: 32 + 8 pad (80 B, 16B-aligned)

    __shared__ short Ah[BM * LSA], Al[BM * LSA];
    __shared__ short Bh[BN * LSA], Bl[BN * LSA];

    const int tid  = threadIdx.x;
    const int lane = tid & 63, wid = tid >> 6;
    const int wm = wid >> 1, wn = wid & 1;
    const int l31 = lane & 31, l5 = lane >> 5;
    const int bm = blockIdx.x * BM;
    const int bn = blockIdx.y * BN;
    const size_t aLo = (size_t)M * K;
    const size_t bLo = (size_t)Nc * K;

    f32x16 acc[2][FNv] = {};

    for (int k0 = 0; k0 < K; k0 += BK) {
        // ---- stage A ----
        if (A_SPLIT) {
            #pragma unroll
            for (int it = 0; it < (BM * 4) / 256; ++it) {   // short8 chunks
                int u = it * 256 + tid;
                int m = u >> 2, kc = u & 3;
                int gm = bm + m;
                short8 h8 = {}, l8 = {};
                if (gm < M) {
                    size_t g = (size_t)gm * K + k0 + kc * 8;
                    h8 = *(const short8*)&Asp[g];
                    l8 = *(const short8*)&Asp[aLo + g];
                }
                *(short8*)&Ah[m * LSA + kc * 8] = h8;
                *(short8*)&Al[m * LSA + kc * 8] = l8;
            }
        } else {
            #pragma unroll
            for (int it = 0; it < (BM * BK) / (4 * 256); ++it) {
                int u = it * 256 + tid;
                int r = u >> 3, c4 = u & 7;
                int gr = bm + r;
                float4 v = make_float4(0.f, 0.f, 0.f, 0.f);
                if (gr < M) v = *(const float4*)&A[(size_t)gr * K + k0 + c4 * 4];
                s16x4 hi4, lo4;
                float f[4] = {v.x, v.y, v.z, v.w};
                #pragma unroll
                for (int i = 0; i < 4; ++i) {
                    unsigned hb_ = bf_hi(f[i]);
                    hi4[i] = (short)hb_;
                    lo4[i] = (short)bf_hi(f[i] - bf_f(hb_));
                }
                *(s16x4*)&Ah[r * LSA + c4 * 4] = hi4;
                *(s16x4*)&Al[r * LSA + c4 * 4] = lo4;
            }
        }
        // ---- stage B (pre-split, pre-transposed: pure copy) ----
        #pragma unroll
        for (int it = 0; it < (BN * 4) / 256; ++it) {
            int u = it * 256 + tid;
            int nn = u >> 2, kc = u & 3;
            size_t g = (size_t)(bn + nn) * K + k0 + kc * 8;
            *(short8*)&Bh[nn * LSA + kc * 8] = *(const short8*)&Bt[g];
            *(short8*)&Bl[nn * LSA + kc * 8] = *(const short8*)&Bt[bLo + g];
        }
        __syncthreads();
        // ---- fragments + MFMA (two k-halves of 16) ----
        #pragma unroll
        for (int kh = 0; kh < 2; ++kh) {
            const int kcol = kh * 16 + l5 * 8;
            bf16x8 ah[2], al[2], bh[FNv], bl[FNv];
            #pragma unroll
            for (int fm = 0; fm < 2; ++fm) {
                int row = wm * 64 + fm * 32 + l31;
                ah[fm] = __builtin_bit_cast(bf16x8, *(const short8*)&Ah[row * LSA + kcol]);
                al[fm] = __builtin_bit_cast(bf16x8, *(const short8*)&Al[row * LSA + kcol]);
            }
            #pragma unroll
            for (int fn = 0; fn < FNv; ++fn) {
                int col = wn * WN + fn * 32 + l31;
                bh[fn] = __builtin_bit_cast(bf16x8, *(const short8*)&Bh[col * LSA + kcol]);
                bl[fn] = __builtin_bit_cast(bf16x8, *(const short8*)&Bl[col * LSA + kcol]);
            }
            #pragma unroll
            for (int fm = 0; fm < 2; ++fm)
                #pragma unroll
                for (int fn = 0; fn < FNv; ++fn) {
                    acc[fm][fn] = __builtin_amdgcn_mfma_f32_32x32x16_bf16(
                        al[fm], bh[fn], acc[fm][fn], 0, 0, 0);
                    acc[fm][fn] = __builtin_amdgcn_mfma_f32_32x32x16_bf16(
                        ah[fm], bl[fn], acc[fm][fn], 0, 0, 0);
                    acc[fm][fn] = __builtin_amdgcn_mfma_f32_32x32x16_bf16(
                        ah[fm], bh[fn], acc[fm][fn], 0, 0, 0);
                }
        }
        __syncthreads();
    }
    // ---- epilogue: D mapping col=lane&31, row=(j&3)+8*(j>>2)+4*(lane>>5) ----
    const size_t loOff = (size_t)M * Nc;
    #pragma unroll
    for (int fm = 0; fm < 2; ++fm)
        #pragma unroll
        for (int fn = 0; fn < FNv; ++fn) {
            int ncol = bn + wn * WN + fn * 32 + l31;
            float bv = BIAS ? bias[ncol] : 0.f;
            #pragma unroll
            for (int j = 0; j < 16; ++j) {
                int gm = bm + wm * 64 + fm * 32 + (j & 3) + 8 * (j >> 2) + 4 * l5;
                if (gm >= M) continue;
                float v = acc[fm][fn][j] + bv;
                if (RELU_O) v = fmaxf(v, 0.f);
                if (OUT_SPLIT) {
                    unsigned hb_ = bf_hi(v);
                    Cs[(size_t)gm * Nc + ncol] = (ushort_t)hb_;
                    Cs[loOff + (size_t)gm * Nc + ncol] = (ushort_t)bf_hi(v - bf_f(hb_));
                } else {
                    C[(size_t)gm * Nc + ncol] = v;
                }
            }
        }
}

// ---------------------------------------------------------------- launch
extern "C" void kernel_launch(void* const* d_in, const int* in_sizes, int n_in,
                              void* d_out, int out_size, void* d_ws, size_t ws_size,
                              hipStream_t stream) {
    const float* x      = (const float*)d_in[0];
    const int*   edge   = (const int*)d_in[1];
    const float* W_conv = (const float*)d_in[2];
    const float* b_conv = (const float*)d_in[3];
    const float* W_lin  = (const float*)d_in[4];
    const float* b_lin  = (const float*)d_in[5];
    const float* W_dec1 = (const float*)d_in[6];
    const float* b_dec1 = (const float*)d_in[7];
    const float* W_dec2 = (const float*)d_in[8];
    const float* b_dec2 = (const float*)d_in[9];
    float* out = (float*)d_out;

    const int Nn = in_sizes[0] / N_DIM;    // 100000
    const int E  = in_sizes[1] / 2;        // 1600000
    const int* src = edge;
    const int* dst = edge + E;

    // ws layout (bytes):
    // [weight planes 320K][hslot 51.2M: h planes -> z planes]
    // [raslot 51.2M: ra planes -> d planes][csr 12.8M + aux ~1.6M]
    ushort_t* wc_t  = (ushort_t*)d_ws;                 // 2*256*128
    ushort_t* wl_t  = wc_t  + 2 * 256 * 128;           // 2*128*64
    ushort_t* wd1_t = wl_t  + 2 * 128 * 64;            // 2*64*128
    ushort_t* wd2_t = wd1_t + 2 * 64 * 128;            // 2*128*256
    ushort_t* hsl   = wd2_t + 2 * 128 * 256;           // h planes / z planes
    ushort_t* rasl  = hsl + (size_t)2 * Nn * H0;       // ra planes / d planes
    int2*  csr      = (int2*)(rasl + (size_t)2 * Nn * H0);
    int*   cursor   = (int*)(csr + E);
    int*   row_ptr  = cursor + Nn;
    int*   cnt      = row_ptr + Nn + 1;
    float* dis      = (float*)(cnt + Nn);
    int*   blockSum = (int*)(dis + Nn);

    const int nb = (Nn + 255) / 256;
    const int gM = (Nn + 127) / 128;       // 782

    // 0. weight planes (once per launch; tiny)
    transpose_split<<<(256 * 128 + 255) / 256, 256, 0, stream>>>(W_conv, wc_t, wc_t + 256 * 128, N_DIM, H0);
    transpose_split<<<(128 * 64 + 255) / 256, 256, 0, stream>>>(W_lin, wl_t, wl_t + 128 * 64, H0, H1);
    transpose_split<<<(64 * 128 + 255) / 256, 256, 0, stream>>>(W_dec1, wd1_t, wd1_t + 64 * 128, H1, H0);
    transpose_split<<<(128 * 256 + 255) / 256, 256, 0, stream>>>(W_dec2, wd2_t, wd2_t + 128 * 256, H0, N_DIM);
    // 1. degree + scan + dis
    zero_int<<<nb, 256, 0, stream>>>(cnt, Nn);
    hist_dst<<<(E + 255) / 256, 256, 0, stream>>>(dst, cnt, E);
    scanA<<<nb, 256, 0, stream>>>(cnt, row_ptr, blockSum, Nn);
    scanB<<<1, 1024, 0, stream>>>(blockSum, nb);
    scanC<<<nb, 256, 0, stream>>>(row_ptr, blockSum, cursor, cnt, dis, Nn, E);
    // 2. h = x @ W_conv -> split planes
    gemm_mfma<128, 128, 32, 0, 0, 0, 1><<<dim3(gM, 1), 256, 0, stream>>>(
        x, nullptr, wc_t, nullptr, nullptr, hsl, Nn, N_DIM, H0);
    // 3. CSR
    build_csr<<<(E + 255) / 256, 256, 0, stream>>>(src, dst, dis, cursor, csr, E);
    // 4. gather -> ra = relu(agg) split planes
    gather_nodes<<<((size_t)Nn * 32 + 255) / 256, 256, 0, stream>>>(
        row_ptr, csr, dis, hsl, b_conv, rasl, Nn);
    // 5. z = ra @ W_lin + b_lin -> split planes (overlay hslot)
    gemm_mfma<128, 64, 32, 1, 1, 0, 1><<<dim3(gM, 1), 256, 0, stream>>>(
        nullptr, rasl, wl_t, b_lin, nullptr, hsl, Nn, H0, H1);
    // 6. d = relu(z @ W_dec1 + b_dec1) -> split planes (overlay raslot)
    gemm_mfma<128, 128, 32, 1, 1, 1, 1><<<dim3(gM, 1), 256, 0, stream>>>(
        nullptr, hsl, wd1_t, b_dec1, nullptr, rasl, Nn, H1, H0);
    // 7. out = d @ W_dec2 + b_dec2 (f32)
    gemm_mfma<128, 128, 32, 1, 1, 0, 0><<<dim3(gM, 2), 256, 0, stream>>>(
        nullptr, rasl, wd2_t, b_dec2, out, nullptr, Nn, H0, N_DIM);
}

// Round 6
// 560.244 us; speedup vs baseline: 5.6962x; 1.0266x over previous
//
#include <hip/hip_runtime.h>
#include <hip/hip_bf16.h>

// GCN autoencoder. N=100000, E=1600000, D=256, H0=128, H1=64.
// R6: (1) csr entry 8B->4B (src only) via h'=h*dis prescale in GEMM1 epilogue
//     -> halves build_csr's granule-amplified scatter writes (101->~55 MB);
// (2) GEMM BM 128->64: grid 782->1563, LDS 30720, launch_bounds(256,5)
//     -> ~5 blocks/CU (was 3) to hide latency (GEMM1 was 8.5% MfmaUtil,
//     20% occupancy, grid-limited);
// (3) prep kernel fuses 4x transpose_split + zero_int (16 -> 11 dispatches).

#define N_DIM 256
#define H0 128
#define H1 64

typedef __bf16 bf16x8 __attribute__((ext_vector_type(8)));
typedef short  short8 __attribute__((ext_vector_type(8)));
typedef short  s16x4  __attribute__((ext_vector_type(4)));
typedef float  f32x16 __attribute__((ext_vector_type(16)));
typedef unsigned short ushort_t;

// round-to-nearest-even f32 -> bf16 bits (finite data only)
__device__ inline unsigned bf_hi(float v) {
    unsigned b = __float_as_uint(v);
    return (b + 0x7FFF + ((b >> 16) & 1)) >> 16;
}
__device__ inline float bf_f(unsigned bits) { return __uint_as_float(bits << 16); }

// --------------------------------------------------------------- prep
// One kernel: transpose+split all 4 weights to bf16 hi/lo planes [n][k],
// and zero the degree counters.
__global__ __launch_bounds__(256) void prep(
    const float* __restrict__ Wc, const float* __restrict__ Wl,
    const float* __restrict__ Wd1, const float* __restrict__ Wd2,
    ushort_t* __restrict__ wc, ushort_t* __restrict__ wl,
    ushort_t* __restrict__ wd1, ushort_t* __restrict__ wd2,
    int* __restrict__ cnt, int Nn) {
    const int S1 = 256 * 128, S2 = S1 + 128 * 64, S3 = S2 + 64 * 128, S4 = S3 + 128 * 256;
    int idx = blockIdx.x * 256 + threadIdx.x;
    const float* W; ushort_t* hi; int K, N, loc, planeSz;
    if (idx < S1)      { W = Wc;  hi = wc;  K = 256; N = 128; loc = idx;      planeSz = S1; }
    else if (idx < S2) { W = Wl;  hi = wl;  K = 128; N = 64;  loc = idx - S1; planeSz = 128 * 64; }
    else if (idx < S3) { W = Wd1; hi = wd1; K = 64;  N = 128; loc = idx - S2; planeSz = 64 * 128; }
    else if (idx < S4) { W = Wd2; hi = wd2; K = 128; N = 256; loc = idx - S3; planeSz = 128 * 256; }
    else {
        int i = idx - S4;
        if (i < Nn) cnt[i] = 0;
        return;
    }
    int n = loc / K, k = loc - n * K;
    float v = W[(size_t)k * N + n];
    unsigned h = bf_hi(v);
    hi[loc] = (ushort_t)h;
    hi[planeSz + loc] = (ushort_t)bf_hi(v - bf_f(h));
}

// ---------------------------------------------------------------- CSR build
__global__ __launch_bounds__(256) void hist_dst(const int* __restrict__ dst,
                                                int* __restrict__ cnt, int E) {
    int e = blockIdx.x * 256 + threadIdx.x;
    if (e < E) atomicAdd(&cnt[dst[e]], 1);
}

__global__ __launch_bounds__(256) void scanA(const int* __restrict__ cnt,
                                             int* __restrict__ row_ptr,
                                             int* __restrict__ blockSum, int n) {
    __shared__ int tmp[256];
    int i = blockIdx.x * 256 + threadIdx.x;
    int v = (i < n) ? cnt[i] : 0;
    tmp[threadIdx.x] = v;
    __syncthreads();
    #pragma unroll
    for (int off = 1; off < 256; off <<= 1) {
        int t = (threadIdx.x >= (unsigned)off) ? tmp[threadIdx.x - off] : 0;
        __syncthreads();
        tmp[threadIdx.x] += t;
        __syncthreads();
    }
    if (i < n) row_ptr[i] = tmp[threadIdx.x] - v;
    if (threadIdx.x == 255) blockSum[blockIdx.x] = tmp[255];
}

__global__ __launch_bounds__(1024) void scanB(int* __restrict__ blockSum, int nb) {
    __shared__ int tmp[1024];
    int v = ((int)threadIdx.x < nb) ? blockSum[threadIdx.x] : 0;
    tmp[threadIdx.x] = v;
    __syncthreads();
    #pragma unroll
    for (int off = 1; off < 1024; off <<= 1) {
        int t = (threadIdx.x >= (unsigned)off) ? tmp[threadIdx.x - off] : 0;
        __syncthreads();
        tmp[threadIdx.x] += t;
        __syncthreads();
    }
    if ((int)threadIdx.x < nb) blockSum[threadIdx.x] = tmp[threadIdx.x] - v;
}

__global__ __launch_bounds__(256) void scanC(int* __restrict__ row_ptr,
                                             const int* __restrict__ blockSum,
                                             int* __restrict__ cursor,
                                             const int* __restrict__ cnt,
                                             float* __restrict__ dis, int n, int E) {
    int i = blockIdx.x * 256 + threadIdx.x;
    if (i < n) {
        int v = row_ptr[i] + blockSum[blockIdx.x];
        row_ptr[i] = v;
        cursor[i] = v;
        dis[i] = rsqrtf((float)cnt[i] + 1.0f);
    }
    if (i == 0) row_ptr[n] = E;
}

// 4-byte entries: just the source node (h' already carries dis[src])
__global__ __launch_bounds__(256) void build_csr(const int* __restrict__ src,
                                                 const int* __restrict__ dst,
                                                 int* __restrict__ cursor,
                                                 int* __restrict__ csr, int E) {
    int e = blockIdx.x * 256 + threadIdx.x;
    if (e >= E) return;
    int pos = atomicAdd(&cursor[dst[e]], 1);
    csr[pos] = src[e];
}

// ---------------------------------------------------------------- gather
// ra[c] = relu( dis[c]*( (hi+lo)h'[c] + sum_edges hi(h'[r]) ) + b_conv ), split.
__global__ __launch_bounds__(256) void gather_nodes(
    const int* __restrict__ row_ptr, const int* __restrict__ csr,
    const float* __restrict__ dis, const ushort_t* __restrict__ hb,
    const float* __restrict__ b_conv, ushort_t* __restrict__ ra, int n) {
    int gid  = (blockIdx.x * 256 + threadIdx.x) >> 5;
    int lane = threadIdx.x & 31;
    if (gid >= n) return;
    const size_t loOff = (size_t)n * H0;
    int beg = row_ptr[gid], end = row_ptr[gid + 1];
    float dc = dis[gid];
    const int lo4 = lane * 4;
    ushort4 sh = *(const ushort4*)&hb[(size_t)gid * H0 + lo4];
    ushort4 sl = *(const ushort4*)&hb[loOff + (size_t)gid * H0 + lo4];
    float sx = bf_f(sh.x) + bf_f(sl.x);
    float sy = bf_f(sh.y) + bf_f(sl.y);
    float sz = bf_f(sh.z) + bf_f(sl.z);
    float sw = bf_f(sh.w) + bf_f(sl.w);
    int j = beg;
    for (; j + 2 <= end; j += 2) {
        int r0 = csr[j], r1 = csr[j + 1];
        ushort4 v0 = *(const ushort4*)&hb[(size_t)r0 * H0 + lo4];
        ushort4 v1 = *(const ushort4*)&hb[(size_t)r1 * H0 + lo4];
        sx += bf_f(v0.x) + bf_f(v1.x);
        sy += bf_f(v0.y) + bf_f(v1.y);
        sz += bf_f(v0.z) + bf_f(v1.z);
        sw += bf_f(v0.w) + bf_f(v1.w);
    }
    if (j < end) {
        int r0 = csr[j];
        ushort4 v0 = *(const ushort4*)&hb[(size_t)r0 * H0 + lo4];
        sx += bf_f(v0.x); sy += bf_f(v0.y); sz += bf_f(v0.z); sw += bf_f(v0.w);
    }
    float4 bv = *(const float4*)&b_conv[lo4];
    float ax = fmaxf(fmaf(sx, dc, bv.x), 0.f);
    float ay = fmaxf(fmaf(sy, dc, bv.y), 0.f);
    float az = fmaxf(fmaf(sz, dc, bv.z), 0.f);
    float aw = fmaxf(fmaf(sw, dc, bv.w), 0.f);
    ushort4 h4, l4;
    unsigned t;
    t = bf_hi(ax); h4.x = t; l4.x = (ushort_t)bf_hi(ax - bf_f(t));
    t = bf_hi(ay); h4.y = t; l4.y = (ushort_t)bf_hi(ay - bf_f(t));
    t = bf_hi(az); h4.z = t; l4.z = (ushort_t)bf_hi(az - bf_f(t));
    t = bf_hi(aw); h4.w = t; l4.w = (ushort_t)bf_hi(aw - bf_f(t));
    *(ushort4*)&ra[(size_t)gid * H0 + lo4] = h4;
    *(ushort4*)&ra[loOff + (size_t)gid * H0 + lo4] = l4;
}

// ---------------------------------------------------------------- MFMA GEMM
// C[M,Nc] = act(scale_m * (A @ B) + bias). A: f32 [M][K] (A_SPLIT=0) or
// pre-split bf16 planes (A_SPLIT=1, lo at +M*K). B: pre-split pre-transposed
// planes [Nc][K] (lo at +Nc*K). 3-term split MFMA (~f32 accuracy).
// BM=64: 4 waves 2x2, wave tile 32 x (BN/2), 32x32x16 frags. 1 barrier pair/tile.
template <int BM, int BN, int BK, int A_SPLIT, int BIAS, int RELU_O, int OUT_SPLIT, int OUT_SCALE>
__global__ __launch_bounds__(256, 5) void gemm_mfma(
    const float* __restrict__ A, const ushort_t* __restrict__ Asp,
    const ushort_t* __restrict__ Bt, const float* __restrict__ bias,
    const float* __restrict__ scale_m,
    float* __restrict__ C, ushort_t* __restrict__ Cs, int M, int K, int Nc) {
    constexpr int WN  = BN / 2;
    constexpr int FM  = BM / 64;   // 32x32 frags per wave in m
    constexpr int FNv = WN / 32;   // 32x32 frags per wave in n
    constexpr int LSA = 40;        // bf16 row stride: 32 + 8 pad

    __shared__ short Ah[BM * LSA], Al[BM * LSA];
    __shared__ short Bh[BN * LSA], Bl[BN * LSA];

    const int tid  = threadIdx.x;
    const int lane = tid & 63, wid = tid >> 6;
    const int wm = wid >> 1, wn = wid & 1;
    const int l31 = lane & 31, l5 = lane >> 5;
    const int bm = blockIdx.x * BM;
    const int bn = blockIdx.y * BN;
    const size_t aLo = (size_t)M * K;
    const size_t bLo = (size_t)Nc * K;

    f32x16 acc[FM][FNv] = {};

    for (int k0 = 0; k0 < K; k0 += BK) {
        // ---- stage A ----
        if (A_SPLIT) {
            #pragma unroll
            for (int it = 0; it < (BM * 4) / 256; ++it) {   // short8 chunks
                int u = it * 256 + tid;
                int m = u >> 2, kc = u & 3;
                int gm = bm + m;
                short8 h8 = {}, l8 = {};
                if (gm < M) {
                    size_t g = (size_t)gm * K + k0 + kc * 8;
                    h8 = *(const short8*)&Asp[g];
                    l8 = *(const short8*)&Asp[aLo + g];
                }
                *(short8*)&Ah[m * LSA + kc * 8] = h8;
                *(short8*)&Al[m * LSA + kc * 8] = l8;
            }
        } else {
            #pragma unroll
            for (int it = 0; it < (BM * BK) / (4 * 256); ++it) {
                int u = it * 256 + tid;
                int r = u >> 3, c4 = u & 7;
                int gr = bm + r;
                float4 v = make_float4(0.f, 0.f, 0.f, 0.f);
                if (gr < M) v = *(const float4*)&A[(size_t)gr * K + k0 + c4 * 4];
                s16x4 hi4, lo4;
                float f[4] = {v.x, v.y, v.z, v.w};
                #pragma unroll
                for (int i = 0; i < 4; ++i) {
                    unsigned hb_ = bf_hi(f[i]);
                    hi4[i] = (short)hb_;
                    lo4[i] = (short)bf_hi(f[i] - bf_f(hb_));
                }
                *(s16x4*)&Ah[r * LSA + c4 * 4] = hi4;
                *(s16x4*)&Al[r * LSA + c4 * 4] = lo4;
            }
        }
        // ---- stage B (pure copy of pre-split planes) ----
        #pragma unroll
        for (int it = 0; it < (BN * 4) / 256; ++it) {
            int u = it * 256 + tid;
            int nn = u >> 2, kc = u & 3;
            size_t g = (size_t)(bn + nn) * K + k0 + kc * 8;
            *(short8*)&Bh[nn * LSA + kc * 8] = *(const short8*)&Bt[g];
            *(short8*)&Bl[nn * LSA + kc * 8] = *(const short8*)&Bt[bLo + g];
        }
        __syncthreads();
        // ---- fragments + MFMA (two k-halves of 16) ----
        #pragma unroll
        for (int kh = 0; kh < 2; ++kh) {
            const int kcol = kh * 16 + l5 * 8;
            bf16x8 ah[FM], al[FM], bh[FNv], bl[FNv];
            #pragma unroll
            for (int fm = 0; fm < FM; ++fm) {
                int row = wm * (BM / 2) + fm * 32 + l31;
                ah[fm] = __builtin_bit_cast(bf16x8, *(const short8*)&Ah[row * LSA + kcol]);
                al[fm] = __builtin_bit_cast(bf16x8, *(const short8*)&Al[row * LSA + kcol]);
            }
            #pragma unroll
            for (int fn = 0; fn < FNv; ++fn) {
                int col = wn * WN + fn * 32 + l31;
                bh[fn] = __builtin_bit_cast(bf16x8, *(const short8*)&Bh[col * LSA + kcol]);
                bl[fn] = __builtin_bit_cast(bf16x8, *(const short8*)&Bl[col * LSA + kcol]);
            }
            #pragma unroll
            for (int fm = 0; fm < FM; ++fm)
                #pragma unroll
                for (int fn = 0; fn < FNv; ++fn) {
                    acc[fm][fn] = __builtin_amdgcn_mfma_f32_32x32x16_bf16(
                        al[fm], bh[fn], acc[fm][fn], 0, 0, 0);
                    acc[fm][fn] = __builtin_amdgcn_mfma_f32_32x32x16_bf16(
                        ah[fm], bl[fn], acc[fm][fn], 0, 0, 0);
                    acc[fm][fn] = __builtin_amdgcn_mfma_f32_32x32x16_bf16(
                        ah[fm], bh[fn], acc[fm][fn], 0, 0, 0);
                }
        }
        __syncthreads();
    }
    // ---- epilogue: D mapping col=lane&31, row=(j&3)+8*(j>>2)+4*(lane>>5) ----
    const size_t loOff = (size_t)M * Nc;
    int   ncols[FNv];
    float bvv[FNv];
    #pragma unroll
    for (int fn = 0; fn < FNv; ++fn) {
        ncols[fn] = bn + wn * WN + fn * 32 + l31;
        bvv[fn] = BIAS ? bias[ncols[fn]] : 0.f;
    }
    #pragma unroll
    for (int fm = 0; fm < FM; ++fm)
        #pragma unroll
        for (int j = 0; j < 16; ++j) {
            int gm = bm + wm * (BM / 2) + fm * 32 + (j & 3) + 8 * (j >> 2) + 4 * l5;
            if (gm >= M) continue;
            float sc = OUT_SCALE ? scale_m[gm] : 1.0f;
            #pragma unroll
            for (int fn = 0; fn < FNv; ++fn) {
                float v = fmaf(acc[fm][fn][j], sc, bvv[fn]);
                if (RELU_O) v = fmaxf(v, 0.f);
                if (OUT_SPLIT) {
                    unsigned hb_ = bf_hi(v);
                    Cs[(size_t)gm * Nc + ncols[fn]] = (ushort_t)hb_;
                    Cs[loOff + (size_t)gm * Nc + ncols[fn]] = (ushort_t)bf_hi(v - bf_f(hb_));
                } else {
                    C[(size_t)gm * Nc + ncols[fn]] = v;
                }
            }
        }
}

// ---------------------------------------------------------------- launch
extern "C" void kernel_launch(void* const* d_in, const int* in_sizes, int n_in,
                              void* d_out, int out_size, void* d_ws, size_t ws_size,
                              hipStream_t stream) {
    const float* x      = (const float*)d_in[0];
    const int*   edge   = (const int*)d_in[1];
    const float* W_conv = (const float*)d_in[2];
    const float* b_conv = (const float*)d_in[3];
    const float* W_lin  = (const float*)d_in[4];
    const float* b_lin  = (const float*)d_in[5];
    const float* W_dec1 = (const float*)d_in[6];
    const float* b_dec1 = (const float*)d_in[7];
    const float* W_dec2 = (const float*)d_in[8];
    const float* b_dec2 = (const float*)d_in[9];
    float* out = (float*)d_out;

    const int Nn = in_sizes[0] / N_DIM;    // 100000
    const int E  = in_sizes[1] / 2;        // 1600000
    const int* src = edge;
    const int* dst = edge + E;

    // ws: [weight planes 320K][hslot 51.2M: h' planes -> z planes]
    //     [raslot 51.2M: ra planes -> d planes][csr 6.4M][aux ~1.6M]
    ushort_t* wc_t  = (ushort_t*)d_ws;                 // 2*256*128
    ushort_t* wl_t  = wc_t  + 2 * 256 * 128;           // 2*128*64
    ushort_t* wd1_t = wl_t  + 2 * 128 * 64;            // 2*64*128
    ushort_t* wd2_t = wd1_t + 2 * 64 * 128;            // 2*128*256
    ushort_t* hsl   = wd2_t + 2 * 128 * 256;           // h' planes / z planes
    ushort_t* rasl  = hsl + (size_t)2 * Nn * H0;       // ra planes / d planes
    int*   csr      = (int*)(rasl + (size_t)2 * Nn * H0);
    int*   cursor   = csr + E;
    int*   row_ptr  = cursor + Nn;
    int*   cnt      = row_ptr + Nn + 1;
    float* dis      = (float*)(cnt + Nn);
    int*   blockSum = (int*)(dis + Nn);

    const int nb = (Nn + 255) / 256;
    const int gM = (Nn + 63) / 64;         // 1563 row-blocks (BM=64)

    // 0. weights -> planes, cnt -> 0 (one kernel)
    const int prepTot = 256 * 128 + 128 * 64 + 64 * 128 + 128 * 256 + Nn;
    prep<<<(prepTot + 255) / 256, 256, 0, stream>>>(
        W_conv, W_lin, W_dec1, W_dec2, wc_t, wl_t, wd1_t, wd2_t, cnt, Nn);
    // 1. degree + scan + dis
    hist_dst<<<(E + 255) / 256, 256, 0, stream>>>(dst, cnt, E);
    scanA<<<nb, 256, 0, stream>>>(cnt, row_ptr, blockSum, Nn);
    scanB<<<1, 1024, 0, stream>>>(blockSum, nb);
    scanC<<<nb, 256, 0, stream>>>(row_ptr, blockSum, cursor, cnt, dis, Nn, E);
    // 2. h' = (x @ W_conv) * dis  -> split planes
    gemm_mfma<64, 128, 32, 0, 0, 0, 1, 1><<<dim3(gM, 1), 256, 0, stream>>>(
        x, nullptr, wc_t, nullptr, dis, nullptr, hsl, Nn, N_DIM, H0);
    // 3. CSR (4B src-only entries)
    build_csr<<<(E + 255) / 256, 256, 0, stream>>>(src, dst, cursor, csr, E);
    // 4. gather -> ra = relu(dis*(self+neigh)+b) split planes
    gather_nodes<<<((size_t)Nn * 32 + 255) / 256, 256, 0, stream>>>(
        row_ptr, csr, dis, hsl, b_conv, rasl, Nn);
    // 5. z = ra @ W_lin + b_lin -> split planes (overlay hslot)
    gemm_mfma<64, 64, 32, 1, 1, 0, 1, 0><<<dim3(gM, 1), 256, 0, stream>>>(
        nullptr, rasl, wl_t, b_lin, nullptr, nullptr, hsl, Nn, H0, H1);
    // 6. d = relu(z @ W_dec1 + b_dec1) -> split planes (overlay raslot)
    gemm_mfma<64, 128, 32, 1, 1, 1, 1, 0><<<dim3(gM, 1), 256, 0, stream>>>(
        nullptr, hsl, wd1_t, b_dec1, nullptr, nullptr, rasl, Nn, H1, H0);
    // 7. out = d @ W_dec2 + b_dec2 (f32)
    gemm_mfma<64, 128, 32, 1, 1, 0, 0, 0><<<dim3(gM, 2), 256, 0, stream>>>(
        nullptr, rasl, wd2_t, b_dec2, nullptr, out, nullptr, Nn, H0, N_DIM);
}

// Round 8
// 436.104 us; speedup vs baseline: 7.3177x; 1.2847x over previous
//
#include <hip/hip_runtime.h>
#include <hip/hip_bf16.h>

// GCN autoencoder. N=100000, E=1600000, D=256, H0=128, H1=64.
// R7 resubmit (R7 bench was GPUAcquisitionTimeout — kernel never ran):
// build_csr's random 4B scatter (1.6M writes x 64B granule = 105 MB, RMW
// -> 128 us) replaced by two-level counting sort by dst:
//   bucket_hist -> bucket_scan -> bucket_scatter (LDS-staged, contiguous
//   per-(block,bucket) runs) -> fine_csr (per-256-node bucket, L2-local)
// Also deletes hist_dst + scanA/B/C (deg derived from row_ptr).
// GEMMs/gather unchanged from R6 for attribution.

#define N_DIM 256
#define H0 128
#define H1 64
#define CHUNK 8192       // edges per bucket_scatter block

typedef __bf16 bf16x8 __attribute__((ext_vector_type(8)));
typedef short  short8 __attribute__((ext_vector_type(8)));
typedef short  s16x4  __attribute__((ext_vector_type(4)));
typedef float  f32x16 __attribute__((ext_vector_type(16)));
typedef unsigned short ushort_t;

// round-to-nearest-even f32 -> bf16 bits (finite data only)
__device__ inline unsigned bf_hi(float v) {
    unsigned b = __float_as_uint(v);
    return (b + 0x7FFF + ((b >> 16) & 1)) >> 16;
}
__device__ inline float bf_f(unsigned bits) { return __uint_as_float(bits << 16); }

// --------------------------------------------------------------- prep
// transpose+split all 4 weights to bf16 hi/lo planes [n][k]; zero bucket totals.
__global__ __launch_bounds__(256) void prep(
    const float* __restrict__ Wc, const float* __restrict__ Wl,
    const float* __restrict__ Wd1, const float* __restrict__ Wd2,
    ushort_t* __restrict__ wc, ushort_t* __restrict__ wl,
    ushort_t* __restrict__ wd1, ushort_t* __restrict__ wd2,
    int* __restrict__ tot, int nbk) {
    const int S1 = 256 * 128, S2 = S1 + 128 * 64, S3 = S2 + 64 * 128, S4 = S3 + 128 * 256;
    int idx = blockIdx.x * 256 + threadIdx.x;
    const float* W; ushort_t* hi; int K, N, loc, planeSz;
    if (idx < S1)      { W = Wc;  hi = wc;  K = 256; N = 128; loc = idx;      planeSz = S1; }
    else if (idx < S2) { W = Wl;  hi = wl;  K = 128; N = 64;  loc = idx - S1; planeSz = 128 * 64; }
    else if (idx < S3) { W = Wd1; hi = wd1; K = 64;  N = 128; loc = idx - S2; planeSz = 64 * 128; }
    else if (idx < S4) { W = Wd2; hi = wd2; K = 128; N = 256; loc = idx - S3; planeSz = 128 * 256; }
    else {
        int i = idx - S4;
        if (i < nbk) tot[i] = 0;
        return;
    }
    int n = loc / K, k = loc - n * K;
    float v = W[(size_t)k * N + n];
    unsigned h = bf_hi(v);
    hi[loc] = (ushort_t)h;
    hi[planeSz + loc] = (ushort_t)bf_hi(v - bf_f(h));
}

// --------------------------------------------------- coarse bucket histogram
__global__ __launch_bounds__(256) void bucket_hist(const int* __restrict__ dst,
                                                   int* __restrict__ tot, int E, int nbk) {
    __shared__ int h[512];
    h[threadIdx.x] = 0; h[threadIdx.x + 256] = 0;
    __syncthreads();
    int stride = gridDim.x * 256;
    for (int e = blockIdx.x * 256 + threadIdx.x; e < E; e += stride)
        atomicAdd(&h[dst[e] >> 8], 1);
    __syncthreads();
    #pragma unroll
    for (int q = 0; q < 2; ++q) {
        int b = threadIdx.x + q * 256;
        if (b < nbk && h[b]) atomicAdd(&tot[b], h[b]);
    }
}

// ----------------------------------------- scan bucket totals (1 block, <=512)
__global__ __launch_bounds__(256) void bucket_scan(const int* __restrict__ tot,
                                                   int* __restrict__ bbase,
                                                   int* __restrict__ bcur,
                                                   int* __restrict__ row_ptr,
                                                   int nbk, int Nn, int E) {
    __shared__ int sA[512], sB[512];
    int t = threadIdx.x;
    int v0 = (t < nbk) ? tot[t] : 0;
    int v1 = (t + 256 < nbk) ? tot[t + 256] : 0;
    sA[t] = v0; sA[t + 256] = v1;
    __syncthreads();
    int *a = sA, *b = sB;
    for (int off = 1; off < 512; off <<= 1) {
        b[t]       = a[t]       + (t >= off ? a[t - off] : 0);
        b[t + 256] = a[t + 256] + (t + 256 >= off ? a[t + 256 - off] : 0);
        __syncthreads();
        int* w = a; a = b; b = w;
    }
    if (t < nbk)       { bbase[t] = a[t] - v0;             bcur[t] = a[t] - v0; }
    if (t + 256 < nbk) { bbase[t + 256] = a[t + 256] - v1; bcur[t + 256] = a[t + 256] - v1; }
    if (t == 0) { bbase[nbk] = E; row_ptr[Nn] = E; }
}

// --------------------------------------------------- coarse scatter (staged)
// pack = (src << 8) | (dst & 255); bucket = dst >> 8. Contiguous run per
// (block,bucket) -> dense line utilization.
__global__ __launch_bounds__(256) void bucket_scatter(
    const int* __restrict__ src, const int* __restrict__ dst,
    int* __restrict__ bcur, int* __restrict__ tmp, int E, int nbk) {
    __shared__ int pk[CHUNK];
    __shared__ ushort_t bk[CHUNK];
    __shared__ int hcnt[512], wcur[512];
    int base = blockIdx.x * CHUNK;
    int cnt = min(CHUNK, E - base);
    hcnt[threadIdx.x] = 0; hcnt[threadIdx.x + 256] = 0;
    __syncthreads();
    for (int i = threadIdx.x; i < cnt; i += 256) {
        int s = src[base + i], d = dst[base + i];
        int b = d >> 8;
        pk[i] = (s << 8) | (d & 255);
        bk[i] = (ushort_t)b;
        atomicAdd(&hcnt[b], 1);
    }
    __syncthreads();
    #pragma unroll
    for (int q = 0; q < 2; ++q) {
        int b = threadIdx.x + q * 256;
        if (b < nbk) {
            int c = hcnt[b];
            wcur[b] = c ? atomicAdd(&bcur[b], c) : 0;
        }
    }
    __syncthreads();
    for (int i = threadIdx.x; i < cnt; i += 256) {
        int b = bk[i];
        int p = atomicAdd(&wcur[b], 1);
        tmp[p] = pk[i];
    }
}

// ------------------------------------------- fine CSR within each 256-node bucket
__global__ __launch_bounds__(256) void fine_csr(const int* __restrict__ bbase,
                                                const int* __restrict__ tmp,
                                                int* __restrict__ csr,
                                                int* __restrict__ row_ptr, int Nn) {
    __shared__ int fcnt[256], sA[256], sB[256], fcur[256];
    int b = blockIdx.x;
    int rb = bbase[b], re = bbase[b + 1];
    int t = threadIdx.x;
    fcnt[t] = 0;
    __syncthreads();
    for (int i = rb + t; i < re; i += 256)
        atomicAdd(&fcnt[tmp[i] & 255], 1);
    __syncthreads();
    sA[t] = fcnt[t];
    __syncthreads();
    int *a = sA, *bb = sB;
    for (int off = 1; off < 256; off <<= 1) {
        bb[t] = a[t] + (t >= off ? a[t - off] : 0);
        __syncthreads();
        int* w = a; a = bb; bb = w;
    }
    int ex = a[t] - fcnt[t];          // exclusive
    fcur[t] = ex;
    int node = (b << 8) + t;
    if (node < Nn) row_ptr[node] = rb + ex;
    __syncthreads();
    for (int i = rb + t; i < re; i += 256) {
        int pkv = tmp[i];
        int p = atomicAdd(&fcur[pkv & 255], 1);
        csr[rb + p] = (unsigned)pkv >> 8;
    }
}

// ---------------------------------------------------------------- dis
__global__ __launch_bounds__(256) void calc_dis(const int* __restrict__ row_ptr,
                                                float* __restrict__ dis, int Nn) {
    int i = blockIdx.x * 256 + threadIdx.x;
    if (i < Nn) dis[i] = rsqrtf((float)(row_ptr[i + 1] - row_ptr[i]) + 1.0f);
}

// ---------------------------------------------------------------- gather
// ra[c] = relu( dis[c]*( (hi+lo)h'[c] + sum_edges hi(h'[r]) ) + b_conv ), split.
__global__ __launch_bounds__(256) void gather_nodes(
    const int* __restrict__ row_ptr, const int* __restrict__ csr,
    const float* __restrict__ dis, const ushort_t* __restrict__ hb,
    const float* __restrict__ b_conv, ushort_t* __restrict__ ra, int n) {
    int gid  = (blockIdx.x * 256 + threadIdx.x) >> 5;
    int lane = threadIdx.x & 31;
    if (gid >= n) return;
    const size_t loOff = (size_t)n * H0;
    int beg = row_ptr[gid], end = row_ptr[gid + 1];
    float dc = dis[gid];
    const int lo4 = lane * 4;
    ushort4 sh = *(const ushort4*)&hb[(size_t)gid * H0 + lo4];
    ushort4 sl = *(const ushort4*)&hb[loOff + (size_t)gid * H0 + lo4];
    float sx = bf_f(sh.x) + bf_f(sl.x);
    float sy = bf_f(sh.y) + bf_f(sl.y);
    float sz = bf_f(sh.z) + bf_f(sl.z);
    float sw = bf_f(sh.w) + bf_f(sl.w);
    int j = beg;
    for (; j + 2 <= end; j += 2) {
        int r0 = csr[j], r1 = csr[j + 1];
        ushort4 v0 = *(const ushort4*)&hb[(size_t)r0 * H0 + lo4];
        ushort4 v1 = *(const ushort4*)&hb[(size_t)r1 * H0 + lo4];
        sx += bf_f(v0.x) + bf_f(v1.x);
        sy += bf_f(v0.y) + bf_f(v1.y);
        sz += bf_f(v0.z) + bf_f(v1.z);
        sw += bf_f(v0.w) + bf_f(v1.w);
    }
    if (j < end) {
        int r0 = csr[j];
        ushort4 v0 = *(const ushort4*)&hb[(size_t)r0 * H0 + lo4];
        sx += bf_f(v0.x); sy += bf_f(v0.y); sz += bf_f(v0.z); sw += bf_f(v0.w);
    }
    float4 bv = *(const float4*)&b_conv[lo4];
    float ax = fmaxf(fmaf(sx, dc, bv.x), 0.f);
    float ay = fmaxf(fmaf(sy, dc, bv.y), 0.f);
    float az = fmaxf(fmaf(sz, dc, bv.z), 0.f);
    float aw = fmaxf(fmaf(sw, dc, bv.w), 0.f);
    ushort4 h4, l4;
    unsigned t;
    t = bf_hi(ax); h4.x = t; l4.x = (ushort_t)bf_hi(ax - bf_f(t));
    t = bf_hi(ay); h4.y = t; l4.y = (ushort_t)bf_hi(ay - bf_f(t));
    t = bf_hi(az); h4.z = t; l4.z = (ushort_t)bf_hi(az - bf_f(t));
    t = bf_hi(aw); h4.w = t; l4.w = (ushort_t)bf_hi(aw - bf_f(t));
    *(ushort4*)&ra[(size_t)gid * H0 + lo4] = h4;
    *(ushort4*)&ra[loOff + (size_t)gid * H0 + lo4] = l4;
}

// ---------------------------------------------------------------- MFMA GEMM
// C[M,Nc] = act(scale_m * (A @ B) + bias). A: f32 [M][K] (A_SPLIT=0) or
// pre-split bf16 planes (A_SPLIT=1, lo at +M*K). B: pre-split pre-transposed
// planes [Nc][K] (lo at +Nc*K). 3-term split MFMA (~f32 accuracy).
// BM=64: 4 waves 2x2, wave tile 32 x (BN/2), 32x32x16 frags.
template <int BM, int BN, int BK, int A_SPLIT, int BIAS, int RELU_O, int OUT_SPLIT, int OUT_SCALE>
__global__ __launch_bounds__(256, 5) void gemm_mfma(
    const float* __restrict__ A, const ushort_t* __restrict__ Asp,
    const ushort_t* __restrict__ Bt, const float* __restrict__ bias,
    const float* __restrict__ scale_m,
    float* __restrict__ C, ushort_t* __restrict__ Cs, int M, int K, int Nc) {
    constexpr int WN  = BN / 2;
    constexpr int FM  = BM / 64;
    constexpr int FNv = WN / 32;
    constexpr int LSA = 40;        // bf16 row stride: 32 + 8 pad

    __shared__ short Ah[BM * LSA], Al[BM * LSA];
    __shared__ short Bh[BN * LSA], Bl[BN * LSA];

    const int tid  = threadIdx.x;
    const int lane = tid & 63, wid = tid >> 6;
    const int wm = wid >> 1, wn = wid & 1;
    const int l31 = lane & 31, l5 = lane >> 5;
    const int bm = blockIdx.x * BM;
    const int bn = blockIdx.y * BN;
    const size_t aLo = (size_t)M * K;
    const size_t bLo = (size_t)Nc * K;

    f32x16 acc[FM][FNv] = {};

    for (int k0 = 0; k0 < K; k0 += BK) {
        if (A_SPLIT) {
            #pragma unroll
            for (int it = 0; it < (BM * 4) / 256; ++it) {
                int u = it * 256 + tid;
                int m = u >> 2, kc = u & 3;
                int gm = bm + m;
                short8 h8 = {}, l8 = {};
                if (gm < M) {
                    size_t g = (size_t)gm * K + k0 + kc * 8;
                    h8 = *(const short8*)&Asp[g];
                    l8 = *(const short8*)&Asp[aLo + g];
                }
                *(short8*)&Ah[m * LSA + kc * 8] = h8;
                *(short8*)&Al[m * LSA + kc * 8] = l8;
            }
        } else {
            #pragma unroll
            for (int it = 0; it < (BM * BK) / (4 * 256); ++it) {
                int u = it * 256 + tid;
                int r = u >> 3, c4 = u & 7;
                int gr = bm + r;
                float4 v = make_float4(0.f, 0.f, 0.f, 0.f);
                if (gr < M) v = *(const float4*)&A[(size_t)gr * K + k0 + c4 * 4];
                s16x4 hi4, lo4;
                float f[4] = {v.x, v.y, v.z, v.w};
                #pragma unroll
                for (int i = 0; i < 4; ++i) {
                    unsigned hb_ = bf_hi(f[i]);
                    hi4[i] = (short)hb_;
                    lo4[i] = (short)bf_hi(f[i] - bf_f(hb_));
                }
                *(s16x4*)&Ah[r * LSA + c4 * 4] = hi4;
                *(s16x4*)&Al[r * LSA + c4 * 4] = lo4;
            }
        }
        #pragma unroll
        for (int it = 0; it < (BN * 4) / 256; ++it) {
            int u = it * 256 + tid;
            int nn = u >> 2, kc = u & 3;
            size_t g = (size_t)(bn + nn) * K + k0 + kc * 8;
            *(short8*)&Bh[nn * LSA + kc * 8] = *(const short8*)&Bt[g];
            *(short8*)&Bl[nn * LSA + kc * 8] = *(const short8*)&Bt[bLo + g];
        }
        __syncthreads();
        #pragma unroll
        for (int kh = 0; kh < 2; ++kh) {
            const int kcol = kh * 16 + l5 * 8;
            bf16x8 ah[FM], al[FM], bh[FNv], bl[FNv];
            #pragma unroll
            for (int fm = 0; fm < FM; ++fm) {
                int row = wm * (BM / 2) + fm * 32 + l31;
                ah[fm] = __builtin_bit_cast(bf16x8, *(const short8*)&Ah[row * LSA + kcol]);
                al[fm] = __builtin_bit_cast(bf16x8, *(const short8*)&Al[row * LSA + kcol]);
            }
            #pragma unroll
            for (int fn = 0; fn < FNv; ++fn) {
                int col = wn * WN + fn * 32 + l31;
                bh[fn] = __builtin_bit_cast(bf16x8, *(const short8*)&Bh[col * LSA + kcol]);
                bl[fn] = __builtin_bit_cast(bf16x8, *(const short8*)&Bl[col * LSA + kcol]);
            }
            #pragma unroll
            for (int fm = 0; fm < FM; ++fm)
                #pragma unroll
                for (int fn = 0; fn < FNv; ++fn) {
                    acc[fm][fn] = __builtin_amdgcn_mfma_f32_32x32x16_bf16(
                        al[fm], bh[fn], acc[fm][fn], 0, 0, 0);
                    acc[fm][fn] = __builtin_amdgcn_mfma_f32_32x32x16_bf16(
                        ah[fm], bl[fn], acc[fm][fn], 0, 0, 0);
                    acc[fm][fn] = __builtin_amdgcn_mfma_f32_32x32x16_bf16(
                        ah[fm], bh[fn], acc[fm][fn], 0, 0, 0);
                }
        }
        __syncthreads();
    }
    const size_t loOff = (size_t)M * Nc;
    int   ncols[FNv];
    float bvv[FNv];
    #pragma unroll
    for (int fn = 0; fn < FNv; ++fn) {
        ncols[fn] = bn + wn * WN + fn * 32 + l31;
        bvv[fn] = BIAS ? bias[ncols[fn]] : 0.f;
    }
    #pragma unroll
    for (int fm = 0; fm < FM; ++fm)
        #pragma unroll
        for (int j = 0; j < 16; ++j) {
            int gm = bm + wm * (BM / 2) + fm * 32 + (j & 3) + 8 * (j >> 2) + 4 * l5;
            if (gm >= M) continue;
            float sc = OUT_SCALE ? scale_m[gm] : 1.0f;
            #pragma unroll
            for (int fn = 0; fn < FNv; ++fn) {
                float v = fmaf(acc[fm][fn][j], sc, bvv[fn]);
                if (RELU_O) v = fmaxf(v, 0.f);
                if (OUT_SPLIT) {
                    unsigned hb_ = bf_hi(v);
                    Cs[(size_t)gm * Nc + ncols[fn]] = (ushort_t)hb_;
                    Cs[loOff + (size_t)gm * Nc + ncols[fn]] = (ushort_t)bf_hi(v - bf_f(hb_));
                } else {
                    C[(size_t)gm * Nc + ncols[fn]] = v;
                }
            }
        }
}

// ---------------------------------------------------------------- launch
extern "C" void kernel_launch(void* const* d_in, const int* in_sizes, int n_in,
                              void* d_out, int out_size, void* d_ws, size_t ws_size,
                              hipStream_t stream) {
    const float* x      = (const float*)d_in[0];
    const int*   edge   = (const int*)d_in[1];
    const float* W_conv = (const float*)d_in[2];
    const float* b_conv = (const float*)d_in[3];
    const float* W_lin  = (const float*)d_in[4];
    const float* b_lin  = (const float*)d_in[5];
    const float* W_dec1 = (const float*)d_in[6];
    const float* b_dec1 = (const float*)d_in[7];
    const float* W_dec2 = (const float*)d_in[8];
    const float* b_dec2 = (const float*)d_in[9];
    float* out = (float*)d_out;

    const int Nn = in_sizes[0] / N_DIM;    // 100000
    const int E  = in_sizes[1] / 2;        // 1600000
    const int* src = edge;
    const int* dst = edge + E;
    const int nbk = (Nn + 255) >> 8;       // 391 buckets of 256 nodes

    // ws: [weight planes 320K][hslot 51.2M][raslot 51.2M][tmp 6.4M][csr 6.4M][aux]
    ushort_t* wc_t  = (ushort_t*)d_ws;
    ushort_t* wl_t  = wc_t  + 2 * 256 * 128;
    ushort_t* wd1_t = wl_t  + 2 * 128 * 64;
    ushort_t* wd2_t = wd1_t + 2 * 64 * 128;
    ushort_t* hsl   = wd2_t + 2 * 128 * 256;
    ushort_t* rasl  = hsl + (size_t)2 * Nn * H0;
    int*   tmp      = (int*)(rasl + (size_t)2 * Nn * H0);
    int*   csr      = tmp + E;
    int*   tot      = csr + E;             // nbk
    int*   bbase    = tot + nbk;           // nbk+1
    int*   bcur     = bbase + nbk + 1;     // nbk
    int*   row_ptr  = bcur + nbk;          // Nn+1
    float* dis      = (float*)(row_ptr + Nn + 1);  // Nn

    const int gM = (Nn + 63) / 64;         // 1563 row-blocks (BM=64)

    // 0. weights -> planes; zero bucket totals
    const int prepTot = 256 * 128 + 128 * 64 + 64 * 128 + 128 * 256 + nbk;
    prep<<<(prepTot + 255) / 256, 256, 0, stream>>>(
        W_conv, W_lin, W_dec1, W_dec2, wc_t, wl_t, wd1_t, wd2_t, tot, nbk);
    // 1. coarse histogram / scan / staged scatter / fine sort
    bucket_hist<<<512, 256, 0, stream>>>(dst, tot, E, nbk);
    bucket_scan<<<1, 256, 0, stream>>>(tot, bbase, bcur, row_ptr, nbk, Nn, E);
    bucket_scatter<<<(E + CHUNK - 1) / CHUNK, 256, 0, stream>>>(src, dst, bcur, tmp, E, nbk);
    fine_csr<<<nbk, 256, 0, stream>>>(bbase, tmp, csr, row_ptr, Nn);
    calc_dis<<<(Nn + 255) / 256, 256, 0, stream>>>(row_ptr, dis, Nn);
    // 2. h' = (x @ W_conv) * dis  -> split planes
    gemm_mfma<64, 128, 32, 0, 0, 0, 1, 1><<<dim3(gM, 1), 256, 0, stream>>>(
        x, nullptr, wc_t, nullptr, dis, nullptr, hsl, Nn, N_DIM, H0);
    // 3. gather -> ra = relu(dis*(self+neigh)+b) split planes
    gather_nodes<<<((size_t)Nn * 32 + 255) / 256, 256, 0, stream>>>(
        row_ptr, csr, dis, hsl, b_conv, rasl, Nn);
    // 4. z = ra @ W_lin + b_lin -> split planes (overlay hslot)
    gemm_mfma<64, 64, 32, 1, 1, 0, 1, 0><<<dim3(gM, 1), 256, 0, stream>>>(
        nullptr, rasl, wl_t, b_lin, nullptr, nullptr, hsl, Nn, H0, H1);
    // 5. d = relu(z @ W_dec1 + b_dec1) -> split planes (overlay raslot)
    gemm_mfma<64, 128, 32, 1, 1, 1, 1, 0><<<dim3(gM, 1), 256, 0, stream>>>(
        nullptr, hsl, wd1_t, b_dec1, nullptr, nullptr, rasl, Nn, H1, H0);
    // 6. out = d @ W_dec2 + b_dec2 (f32)
    gemm_mfma<64, 128, 32, 1, 1, 0, 0, 0><<<dim3(gM, 2), 256, 0, stream>>>(
        nullptr, rasl, wd2_t, b_dec2, nullptr, out, nullptr, Nn, H0, N_DIM);
}

// Round 10
// 429.094 us; speedup vs baseline: 7.4373x; 1.0163x over previous
//
#include <hip/hip_runtime.h>
#include <hip/hip_bf16.h>

// GCN autoencoder. N=100000, E=1600000, D=256, H0=128, H1=64.
// R9 resubmit (R9 bench was an infra failure — container died; kernel never ran):
// GEMM was latency-bound (MfmaUtil 9.5%, VALU 16%, HBM 17%, occ 35% --
// staging loads issued then immediately waited at the barrier each k-tile).
// Change: reg-prefetch software pipeline in gemm_mfma -- global loads for
// tile t+1 issue before tile t's MFMA, regs->LDS at loop top. Plus: calc_dis
// folded into fine_csr (one fewer dispatch). Everything else unchanged (R8).

#define N_DIM 256
#define H0 128
#define H1 64
#define CHUNK 8192       // edges per bucket_scatter block

typedef __bf16 bf16x8 __attribute__((ext_vector_type(8)));
typedef short  short8 __attribute__((ext_vector_type(8)));
typedef short  s16x4  __attribute__((ext_vector_type(4)));
typedef float  f32x16 __attribute__((ext_vector_type(16)));
typedef unsigned short ushort_t;

// round-to-nearest-even f32 -> bf16 bits (finite data only)
__device__ inline unsigned bf_hi(float v) {
    unsigned b = __float_as_uint(v);
    return (b + 0x7FFF + ((b >> 16) & 1)) >> 16;
}
__device__ inline float bf_f(unsigned bits) { return __uint_as_float(bits << 16); }

// --------------------------------------------------------------- prep
__global__ __launch_bounds__(256) void prep(
    const float* __restrict__ Wc, const float* __restrict__ Wl,
    const float* __restrict__ Wd1, const float* __restrict__ Wd2,
    ushort_t* __restrict__ wc, ushort_t* __restrict__ wl,
    ushort_t* __restrict__ wd1, ushort_t* __restrict__ wd2,
    int* __restrict__ tot, int nbk) {
    const int S1 = 256 * 128, S2 = S1 + 128 * 64, S3 = S2 + 64 * 128, S4 = S3 + 128 * 256;
    int idx = blockIdx.x * 256 + threadIdx.x;
    const float* W; ushort_t* hi; int K, N, loc, planeSz;
    if (idx < S1)      { W = Wc;  hi = wc;  K = 256; N = 128; loc = idx;      planeSz = S1; }
    else if (idx < S2) { W = Wl;  hi = wl;  K = 128; N = 64;  loc = idx - S1; planeSz = 128 * 64; }
    else if (idx < S3) { W = Wd1; hi = wd1; K = 64;  N = 128; loc = idx - S2; planeSz = 64 * 128; }
    else if (idx < S4) { W = Wd2; hi = wd2; K = 128; N = 256; loc = idx - S3; planeSz = 128 * 256; }
    else {
        int i = idx - S4;
        if (i < nbk) tot[i] = 0;
        return;
    }
    int n = loc / K, k = loc - n * K;
    float v = W[(size_t)k * N + n];
    unsigned h = bf_hi(v);
    hi[loc] = (ushort_t)h;
    hi[planeSz + loc] = (ushort_t)bf_hi(v - bf_f(h));
}

// --------------------------------------------------- coarse bucket histogram
__global__ __launch_bounds__(256) void bucket_hist(const int* __restrict__ dst,
                                                   int* __restrict__ tot, int E, int nbk) {
    __shared__ int h[512];
    h[threadIdx.x] = 0; h[threadIdx.x + 256] = 0;
    __syncthreads();
    int stride = gridDim.x * 256;
    for (int e = blockIdx.x * 256 + threadIdx.x; e < E; e += stride)
        atomicAdd(&h[dst[e] >> 8], 1);
    __syncthreads();
    #pragma unroll
    for (int q = 0; q < 2; ++q) {
        int b = threadIdx.x + q * 256;
        if (b < nbk && h[b]) atomicAdd(&tot[b], h[b]);
    }
}

// ----------------------------------------- scan bucket totals (1 block, <=512)
__global__ __launch_bounds__(256) void bucket_scan(const int* __restrict__ tot,
                                                   int* __restrict__ bbase,
                                                   int* __restrict__ bcur,
                                                   int* __restrict__ row_ptr,
                                                   int nbk, int Nn, int E) {
    __shared__ int sA[512], sB[512];
    int t = threadIdx.x;
    int v0 = (t < nbk) ? tot[t] : 0;
    int v1 = (t + 256 < nbk) ? tot[t + 256] : 0;
    sA[t] = v0; sA[t + 256] = v1;
    __syncthreads();
    int *a = sA, *b = sB;
    for (int off = 1; off < 512; off <<= 1) {
        b[t]       = a[t]       + (t >= off ? a[t - off] : 0);
        b[t + 256] = a[t + 256] + (t + 256 >= off ? a[t + 256 - off] : 0);
        __syncthreads();
        int* w = a; a = b; b = w;
    }
    if (t < nbk)       { bbase[t] = a[t] - v0;             bcur[t] = a[t] - v0; }
    if (t + 256 < nbk) { bbase[t + 256] = a[t + 256] - v1; bcur[t + 256] = a[t + 256] - v1; }
    if (t == 0) { bbase[nbk] = E; row_ptr[Nn] = E; }
}

// --------------------------------------------------- coarse scatter (staged)
__global__ __launch_bounds__(256) void bucket_scatter(
    const int* __restrict__ src, const int* __restrict__ dst,
    int* __restrict__ bcur, int* __restrict__ tmp, int E, int nbk) {
    __shared__ int pk[CHUNK];
    __shared__ ushort_t bk[CHUNK];
    __shared__ int hcnt[512], wcur[512];
    int base = blockIdx.x * CHUNK;
    int cnt = min(CHUNK, E - base);
    hcnt[threadIdx.x] = 0; hcnt[threadIdx.x + 256] = 0;
    __syncthreads();
    for (int i = threadIdx.x; i < cnt; i += 256) {
        int s = src[base + i], d = dst[base + i];
        int b = d >> 8;
        pk[i] = (s << 8) | (d & 255);
        bk[i] = (ushort_t)b;
        atomicAdd(&hcnt[b], 1);
    }
    __syncthreads();
    #pragma unroll
    for (int q = 0; q < 2; ++q) {
        int b = threadIdx.x + q * 256;
        if (b < nbk) {
            int c = hcnt[b];
            wcur[b] = c ? atomicAdd(&bcur[b], c) : 0;
        }
    }
    __syncthreads();
    for (int i = threadIdx.x; i < cnt; i += 256) {
        int b = bk[i];
        int p = atomicAdd(&wcur[b], 1);
        tmp[p] = pk[i];
    }
}

// ------------------------------- fine CSR within each 256-node bucket (+ dis)
__global__ __launch_bounds__(256) void fine_csr(const int* __restrict__ bbase,
                                                const int* __restrict__ tmp,
                                                int* __restrict__ csr,
                                                int* __restrict__ row_ptr,
                                                float* __restrict__ dis, int Nn) {
    __shared__ int fcnt[256], sA[256], sB[256], fcur[256];
    int b = blockIdx.x;
    int rb = bbase[b], re = bbase[b + 1];
    int t = threadIdx.x;
    fcnt[t] = 0;
    __syncthreads();
    for (int i = rb + t; i < re; i += 256)
        atomicAdd(&fcnt[tmp[i] & 255], 1);
    __syncthreads();
    sA[t] = fcnt[t];
    __syncthreads();
    int *a = sA, *bb = sB;
    for (int off = 1; off < 256; off <<= 1) {
        bb[t] = a[t] + (t >= off ? a[t - off] : 0);
        __syncthreads();
        int* w = a; a = bb; bb = w;
    }
    int ex = a[t] - fcnt[t];          // exclusive
    fcur[t] = ex;
    int node = (b << 8) + t;
    if (node < Nn) {
        row_ptr[node] = rb + ex;
        dis[node] = rsqrtf((float)fcnt[t] + 1.0f);   // deg + self-loop
    }
    __syncthreads();
    for (int i = rb + t; i < re; i += 256) {
        int pkv = tmp[i];
        int p = atomicAdd(&fcur[pkv & 255], 1);
        csr[rb + p] = (unsigned)pkv >> 8;
    }
}

// ---------------------------------------------------------------- gather
__global__ __launch_bounds__(256) void gather_nodes(
    const int* __restrict__ row_ptr, const int* __restrict__ csr,
    const float* __restrict__ dis, const ushort_t* __restrict__ hb,
    const float* __restrict__ b_conv, ushort_t* __restrict__ ra, int n) {
    int gid  = (blockIdx.x * 256 + threadIdx.x) >> 5;
    int lane = threadIdx.x & 31;
    if (gid >= n) return;
    const size_t loOff = (size_t)n * H0;
    int beg = row_ptr[gid], end = row_ptr[gid + 1];
    float dc = dis[gid];
    const int lo4 = lane * 4;
    ushort4 sh = *(const ushort4*)&hb[(size_t)gid * H0 + lo4];
    ushort4 sl = *(const ushort4*)&hb[loOff + (size_t)gid * H0 + lo4];
    float sx = bf_f(sh.x) + bf_f(sl.x);
    float sy = bf_f(sh.y) + bf_f(sl.y);
    float sz = bf_f(sh.z) + bf_f(sl.z);
    float sw = bf_f(sh.w) + bf_f(sl.w);
    int j = beg;
    for (; j + 2 <= end; j += 2) {
        int r0 = csr[j], r1 = csr[j + 1];
        ushort4 v0 = *(const ushort4*)&hb[(size_t)r0 * H0 + lo4];
        ushort4 v1 = *(const ushort4*)&hb[(size_t)r1 * H0 + lo4];
        sx += bf_f(v0.x) + bf_f(v1.x);
        sy += bf_f(v0.y) + bf_f(v1.y);
        sz += bf_f(v0.z) + bf_f(v1.z);
        sw += bf_f(v0.w) + bf_f(v1.w);
    }
    if (j < end) {
        int r0 = csr[j];
        ushort4 v0 = *(const ushort4*)&hb[(size_t)r0 * H0 + lo4];
        sx += bf_f(v0.x); sy += bf_f(v0.y); sz += bf_f(v0.z); sw += bf_f(v0.w);
    }
    float4 bv = *(const float4*)&b_conv[lo4];
    float ax = fmaxf(fmaf(sx, dc, bv.x), 0.f);
    float ay = fmaxf(fmaf(sy, dc, bv.y), 0.f);
    float az = fmaxf(fmaf(sz, dc, bv.z), 0.f);
    float aw = fmaxf(fmaf(sw, dc, bv.w), 0.f);
    ushort4 h4, l4;
    unsigned t;
    t = bf_hi(ax); h4.x = t; l4.x = (ushort_t)bf_hi(ax - bf_f(t));
    t = bf_hi(ay); h4.y = t; l4.y = (ushort_t)bf_hi(ay - bf_f(t));
    t = bf_hi(az); h4.z = t; l4.z = (ushort_t)bf_hi(az - bf_f(t));
    t = bf_hi(aw); h4.w = t; l4.w = (ushort_t)bf_hi(aw - bf_f(t));
    *(ushort4*)&ra[(size_t)gid * H0 + lo4] = h4;
    *(ushort4*)&ra[loOff + (size_t)gid * H0 + lo4] = l4;
}

// ---------------------------------------------------------------- MFMA GEMM
// Reg-prefetch pipeline: LOAD(t+1) issues before COMPUTE(t); regs->LDS at
// loop top. C = act(scale_m * (A@B) + bias); 3-term split MFMA.
template <int BM, int BN, int BK, int A_SPLIT, int BIAS, int RELU_O, int OUT_SPLIT, int OUT_SCALE>
__global__ __launch_bounds__(256, 5) void gemm_mfma(
    const float* __restrict__ A, const ushort_t* __restrict__ Asp,
    const ushort_t* __restrict__ Bt, const float* __restrict__ bias,
    const float* __restrict__ scale_m,
    float* __restrict__ C, ushort_t* __restrict__ Cs, int M, int K, int Nc) {
    constexpr int WN  = BN / 2;
    constexpr int FM  = BM / 64;
    constexpr int FNv = WN / 32;
    constexpr int LSA = 40;                       // bf16 row stride: 32 + 8 pad
    constexpr int A_IT  = (BM * 4) / 256;         // short8 chunks (A_SPLIT=1)
    constexpr int A_ITF = (BM * BK) / (4 * 256);  // float4 chunks (A_SPLIT=0)
    constexpr int B_IT  = (BN * 4) / 256;

    __shared__ short Ah[BM * LSA], Al[BM * LSA];
    __shared__ short Bh[BN * LSA], Bl[BN * LSA];

    const int tid  = threadIdx.x;
    const int lane = tid & 63, wid = tid >> 6;
    const int wm = wid >> 1, wn = wid & 1;
    const int l31 = lane & 31, l5 = lane >> 5;
    const int bm = blockIdx.x * BM;
    const int bn = blockIdx.y * BN;
    const size_t aLo = (size_t)M * K;
    const size_t bLo = (size_t)Nc * K;

    // staging registers (next-tile prefetch)
    short8 pAh[A_IT], pAl[A_IT];
    float4 pAf[A_ITF];
    short8 pBh[B_IT], pBl[B_IT];

    auto LOADA = [&](int k0) {
        if (A_SPLIT) {
            #pragma unroll
            for (int it = 0; it < A_IT; ++it) {
                int u = it * 256 + tid;
                int m = u >> 2, kc = u & 3;
                int gm = bm + m;
                pAh[it] = short8{}; pAl[it] = short8{};
                if (gm < M) {
                    size_t g = (size_t)gm * K + k0 + kc * 8;
                    pAh[it] = *(const short8*)&Asp[g];
                    pAl[it] = *(const short8*)&Asp[aLo + g];
                }
            }
        } else {
            #pragma unroll
            for (int it = 0; it < A_ITF; ++it) {
                int u = it * 256 + tid;
                int r = u >> 3, c4 = u & 7;
                int gr = bm + r;
                pAf[it] = make_float4(0.f, 0.f, 0.f, 0.f);
                if (gr < M) pAf[it] = *(const float4*)&A[(size_t)gr * K + k0 + c4 * 4];
            }
        }
    };
    auto LOADB = [&](int k0) {
        #pragma unroll
        for (int it = 0; it < B_IT; ++it) {
            int u = it * 256 + tid;
            int nn = u >> 2, kc = u & 3;
            size_t g = (size_t)(bn + nn) * K + k0 + kc * 8;
            pBh[it] = *(const short8*)&Bt[g];
            pBl[it] = *(const short8*)&Bt[bLo + g];
        }
    };
    auto STORE = [&]() {
        if (A_SPLIT) {
            #pragma unroll
            for (int it = 0; it < A_IT; ++it) {
                int u = it * 256 + tid;
                int m = u >> 2, kc = u & 3;
                *(short8*)&Ah[m * LSA + kc * 8] = pAh[it];
                *(short8*)&Al[m * LSA + kc * 8] = pAl[it];
            }
        } else {
            #pragma unroll
            for (int it = 0; it < A_ITF; ++it) {
                int u = it * 256 + tid;
                int r = u >> 3, c4 = u & 7;
                s16x4 hi4, lo4;
                float f[4] = {pAf[it].x, pAf[it].y, pAf[it].z, pAf[it].w};
                #pragma unroll
                for (int i = 0; i < 4; ++i) {
                    unsigned hb_ = bf_hi(f[i]);
                    hi4[i] = (short)hb_;
                    lo4[i] = (short)bf_hi(f[i] - bf_f(hb_));
                }
                *(s16x4*)&Ah[r * LSA + c4 * 4] = hi4;
                *(s16x4*)&Al[r * LSA + c4 * 4] = lo4;
            }
        }
        #pragma unroll
        for (int it = 0; it < B_IT; ++it) {
            int u = it * 256 + tid;
            int nn = u >> 2, kc = u & 3;
            *(short8*)&Bh[nn * LSA + kc * 8] = pBh[it];
            *(short8*)&Bl[nn * LSA + kc * 8] = pBl[it];
        }
    };

    f32x16 acc[FM][FNv] = {};

    LOADA(0); LOADB(0);
    for (int k0 = 0; k0 < K; k0 += BK) {
        STORE();                        // regs (tile t) -> LDS
        __syncthreads();
        int kn = k0 + BK;
        if (kn < K) { LOADA(kn); LOADB(kn); }   // prefetch tile t+1 (hides under MFMA)
        #pragma unroll
        for (int kh = 0; kh < 2; ++kh) {
            const int kcol = kh * 16 + l5 * 8;
            bf16x8 ah[FM], al[FM], bh[FNv], bl[FNv];
            #pragma unroll
            for (int fm = 0; fm < FM; ++fm) {
                int row = wm * (BM / 2) + fm * 32 + l31;
                ah[fm] = __builtin_bit_cast(bf16x8, *(const short8*)&Ah[row * LSA + kcol]);
                al[fm] = __builtin_bit_cast(bf16x8, *(const short8*)&Al[row * LSA + kcol]);
            }
            #pragma unroll
            for (int fn = 0; fn < FNv; ++fn) {
                int col = wn * WN + fn * 32 + l31;
                bh[fn] = __builtin_bit_cast(bf16x8, *(const short8*)&Bh[col * LSA + kcol]);
                bl[fn] = __builtin_bit_cast(bf16x8, *(const short8*)&Bl[col * LSA + kcol]);
            }
            #pragma unroll
            for (int fm = 0; fm < FM; ++fm)
                #pragma unroll
                for (int fn = 0; fn < FNv; ++fn) {
                    acc[fm][fn] = __builtin_amdgcn_mfma_f32_32x32x16_bf16(
                        al[fm], bh[fn], acc[fm][fn], 0, 0, 0);
                    acc[fm][fn] = __builtin_amdgcn_mfma_f32_32x32x16_bf16(
                        ah[fm], bl[fn], acc[fm][fn], 0, 0, 0);
                    acc[fm][fn] = __builtin_amdgcn_mfma_f32_32x32x16_bf16(
                        ah[fm], bh[fn], acc[fm][fn], 0, 0, 0);
                }
        }
        __syncthreads();
    }
    // ---- epilogue: D mapping col=lane&31, row=(j&3)+8*(j>>2)+4*(lane>>5) ----
    const size_t loOff = (size_t)M * Nc;
    int   ncols[FNv];
    float bvv[FNv];
    #pragma unroll
    for (int fn = 0; fn < FNv; ++fn) {
        ncols[fn] = bn + wn * WN + fn * 32 + l31;
        bvv[fn] = BIAS ? bias[ncols[fn]] : 0.f;
    }
    #pragma unroll
    for (int fm = 0; fm < FM; ++fm)
        #pragma unroll
        for (int j = 0; j < 16; ++j) {
            int gm = bm + wm * (BM / 2) + fm * 32 + (j & 3) + 8 * (j >> 2) + 4 * l5;
            if (gm >= M) continue;
            float sc = OUT_SCALE ? scale_m[gm] : 1.0f;
            #pragma unroll
            for (int fn = 0; fn < FNv; ++fn) {
                float v = fmaf(acc[fm][fn][j], sc, bvv[fn]);
                if (RELU_O) v = fmaxf(v, 0.f);
                if (OUT_SPLIT) {
                    unsigned hb_ = bf_hi(v);
                    Cs[(size_t)gm * Nc + ncols[fn]] = (ushort_t)hb_;
                    Cs[loOff + (size_t)gm * Nc + ncols[fn]] = (ushort_t)bf_hi(v - bf_f(hb_));
                } else {
                    C[(size_t)gm * Nc + ncols[fn]] = v;
                }
            }
        }
}

// ---------------------------------------------------------------- launch
extern "C" void kernel_launch(void* const* d_in, const int* in_sizes, int n_in,
                              void* d_out, int out_size, void* d_ws, size_t ws_size,
                              hipStream_t stream) {
    const float* x      = (const float*)d_in[0];
    const int*   edge   = (const int*)d_in[1];
    const float* W_conv = (const float*)d_in[2];
    const float* b_conv = (const float*)d_in[3];
    const float* W_lin  = (const float*)d_in[4];
    const float* b_lin  = (const float*)d_in[5];
    const float* W_dec1 = (const float*)d_in[6];
    const float* b_dec1 = (const float*)d_in[7];
    const float* W_dec2 = (const float*)d_in[8];
    const float* b_dec2 = (const float*)d_in[9];
    float* out = (float*)d_out;

    const int Nn = in_sizes[0] / N_DIM;    // 100000
    const int E  = in_sizes[1] / 2;        // 1600000
    const int* src = edge;
    const int* dst = edge + E;
    const int nbk = (Nn + 255) >> 8;       // 391 buckets of 256 nodes

    // ws: [weight planes 320K][hslot 51.2M][raslot 51.2M][tmp 6.4M][csr 6.4M][aux]
    ushort_t* wc_t  = (ushort_t*)d_ws;
    ushort_t* wl_t  = wc_t  + 2 * 256 * 128;
    ushort_t* wd1_t = wl_t  + 2 * 128 * 64;
    ushort_t* wd2_t = wd1_t + 2 * 64 * 128;
    ushort_t* hsl   = wd2_t + 2 * 128 * 256;
    ushort_t* rasl  = hsl + (size_t)2 * Nn * H0;
    int*   tmp      = (int*)(rasl + (size_t)2 * Nn * H0);
    int*   csr      = tmp + E;
    int*   tot      = csr + E;             // nbk
    int*   bbase    = tot + nbk;           // nbk+1
    int*   bcur     = bbase + nbk + 1;     // nbk
    int*   row_ptr  = bcur + nbk;          // Nn+1
    float* dis      = (float*)(row_ptr + Nn + 1);  // Nn

    const int gM = (Nn + 63) / 64;         // 1563 row-blocks (BM=64)

    // 0. weights -> planes; zero bucket totals
    const int prepTot = 256 * 128 + 128 * 64 + 64 * 128 + 128 * 256 + nbk;
    prep<<<(prepTot + 255) / 256, 256, 0, stream>>>(
        W_conv, W_lin, W_dec1, W_dec2, wc_t, wl_t, wd1_t, wd2_t, tot, nbk);
    // 1. coarse histogram / scan / staged scatter / fine sort (+dis)
    bucket_hist<<<512, 256, 0, stream>>>(dst, tot, E, nbk);
    bucket_scan<<<1, 256, 0, stream>>>(tot, bbase, bcur, row_ptr, nbk, Nn, E);
    bucket_scatter<<<(E + CHUNK - 1) / CHUNK, 256, 0, stream>>>(src, dst, bcur, tmp, E, nbk);
    fine_csr<<<nbk, 256, 0, stream>>>(bbase, tmp, csr, row_ptr, dis, Nn);
    // 2. h' = (x @ W_conv) * dis  -> split planes
    gemm_mfma<64, 128, 32, 0, 0, 0, 1, 1><<<dim3(gM, 1), 256, 0, stream>>>(
        x, nullptr, wc_t, nullptr, dis, nullptr, hsl, Nn, N_DIM, H0);
    // 3. gather -> ra = relu(dis*(self+neigh)+b) split planes
    gather_nodes<<<((size_t)Nn * 32 + 255) / 256, 256, 0, stream>>>(
        row_ptr, csr, dis, hsl, b_conv, rasl, Nn);
    // 4. z = ra @ W_lin + b_lin -> split planes (overlay hslot)
    gemm_mfma<64, 64, 32, 1, 1, 0, 1, 0><<<dim3(gM, 1), 256, 0, stream>>>(
        nullptr, rasl, wl_t, b_lin, nullptr, nullptr, hsl, Nn, H0, H1);
    // 5. d = relu(z @ W_dec1 + b_dec1) -> split planes (overlay raslot)
    gemm_mfma<64, 128, 32, 1, 1, 1, 1, 0><<<dim3(gM, 1), 256, 0, stream>>>(
        nullptr, hsl, wd1_t, b_dec1, nullptr, nullptr, rasl, Nn, H1, H0);
    // 6. out = d @ W_dec2 + b_dec2 (f32)
    gemm_mfma<64, 128, 32, 1, 1, 0, 0, 0><<<dim3(gM, 2), 256, 0, stream>>>(
        nullptr, rasl, wd2_t, b_dec2, nullptr, out, nullptr, Nn, H0, N_DIM);
}